// Round 1
// baseline (289.246 us; speedup 1.0000x reference)
//
#include <hip/hip_runtime.h>

typedef unsigned short u16;
typedef short s8b __attribute__((ext_vector_type(8)));     // 8 x bf16 (as raw shorts)
typedef float f4 __attribute__((ext_vector_type(4)));
typedef unsigned short u16x4 __attribute__((ext_vector_type(4)));
typedef float f32x4 __attribute__((ext_vector_type(4)));

__device__ __forceinline__ u16 f2bf(float f) {
  unsigned int u = __builtin_bit_cast(unsigned int, f);
  u += 0x7fffu + ((u >> 16) & 1u);   // round-to-nearest-even
  return (u16)(u >> 16);
}

// ---------------------------------------------------------------- convert
// emb (3,145,728 f32) + 4 weights (589,824 f32 each) -> bf16 in ws
__global__ __launch_bounds__(256) void cvt_all(
    const float* __restrict__ e, const float* __restrict__ wq,
    const float* __restrict__ wk, const float* __restrict__ wv,
    const float* __restrict__ wo,
    u16* __restrict__ eo, u16* __restrict__ wqo, u16* __restrict__ wko,
    u16* __restrict__ wvo, u16* __restrict__ woo)
{
  const int EQ4 = 786432;   // emb quads
  const int WQ4 = 147456;   // weight quads
  const int TOT = EQ4 + 4 * WQ4;
  int i = blockIdx.x * 256 + threadIdx.x;
  const int stride = gridDim.x * 256;
  for (; i < TOT; i += stride) {
    const float* s; u16* d; int off;
    if (i < EQ4) { s = e; d = eo; off = i; }
    else {
      int j = i - EQ4; int w = j / WQ4; off = j - w * WQ4;
      s = (w == 0) ? wq : (w == 1) ? wk : (w == 2) ? wv : wo;
      d = (w == 0) ? wqo : (w == 1) ? wko : (w == 2) ? wvo : woo;
    }
    f32x4 v = ((const f32x4*)s)[off];
    u16x4 o = { f2bf(v[0]), f2bf(v[1]), f2bf(v[2]), f2bf(v[3]) };
    ((u16x4*)d)[off] = o;
  }
}

// ---------------------------------------------------------------- QKV GEMM
// C[m,n] = sum_k X[m,k] * W[n,k]   (X:[4096,768], W:[768,768] both k-contiguous)
// z=0 -> Q (scaled 1/8, [m][n]), z=1 -> K ([m][n]), z=2 -> V^T ([B,H,64,2048])
__global__ __launch_bounds__(256) void qkv_gemm(
    const u16* __restrict__ X, const u16* __restrict__ Wq,
    const u16* __restrict__ Wk, const u16* __restrict__ Wv,
    u16* __restrict__ Qo, u16* __restrict__ Ko, u16* __restrict__ Vt)
{
  const int lane = threadIdx.x & 63;
  const int wid  = threadIdx.x >> 6;
  const int wr = wid >> 1, wc = wid & 1;
  const int mb = blockIdx.x * 128 + wr * 64;
  const int nb = blockIdx.y * 128 + wc * 64;
  const int z  = blockIdx.z;
  const u16* W = (z == 0) ? Wq : (z == 1) ? Wk : Wv;
  const int lr = lane & 15;
  const int lk = (lane >> 4) << 3;

  const f4 fz = {0.f, 0.f, 0.f, 0.f};
  f4 acc[4][4];
#pragma unroll
  for (int i = 0; i < 4; ++i)
#pragma unroll
    for (int j = 0; j < 4; ++j) acc[i][j] = fz;

  const u16* a0 = X + (size_t)(mb + lr) * 768 + lk;
  const u16* b0 = W + (size_t)(nb + lr) * 768 + lk;

  for (int k0 = 0; k0 < 768; k0 += 32) {
    s8b af[4], bfr[4];
#pragma unroll
    for (int i = 0; i < 4; ++i) af[i]  = *(const s8b*)(a0 + (size_t)i * 16 * 768 + k0);
#pragma unroll
    for (int j = 0; j < 4; ++j) bfr[j] = *(const s8b*)(b0 + (size_t)j * 16 * 768 + k0);
#pragma unroll
    for (int i = 0; i < 4; ++i)
#pragma unroll
      for (int j = 0; j < 4; ++j)
        acc[i][j] = __builtin_amdgcn_mfma_f32_16x16x32_bf16(af[i], bfr[j], acc[i][j], 0, 0, 0);
  }

  const int orow = (lane >> 4) << 2;
  if (z == 2) {
    // V^T: vt[((b*12+h)*64+d)*2048 + s]; 4 regs = 4 consecutive s -> 8B store
#pragma unroll
    for (int i = 0; i < 4; ++i) {
      const int m0 = mb + i * 16 + orow;
      const int bb = m0 >> 11, ss = m0 & 2047;
#pragma unroll
      for (int j = 0; j < 4; ++j) {
        const int n = nb + j * 16 + lr;
        const int h = n >> 6, d = n & 63;
        u16x4 pk = { f2bf(acc[i][j][0]), f2bf(acc[i][j][1]),
                     f2bf(acc[i][j][2]), f2bf(acc[i][j][3]) };
        *(u16x4*)(Vt + (((size_t)(bb * 12 + h) * 64 + d) << 11) + ss) = pk;
      }
    }
  } else {
    u16* O = (z == 0) ? Qo : Ko;
    const float sc = (z == 0) ? 0.125f : 1.0f;   // 1/sqrt(64) folded into Q
#pragma unroll
    for (int i = 0; i < 4; ++i) {
      const int m0 = mb + i * 16 + orow;
#pragma unroll
      for (int j = 0; j < 4; ++j) {
        const int n = nb + j * 16 + lr;
#pragma unroll
        for (int r = 0; r < 4; ++r)
          O[(size_t)(m0 + r) * 768 + n] = f2bf(acc[i][j][r] * sc);
      }
    }
  }
}

// ---------------------------------------------------------------- attention
// 4 independent waves/block, 16 q-rows/wave, KVBLK=64, online softmax.
__global__ __launch_bounds__(256) void attn_kernel(
    const u16* __restrict__ Q, const u16* __restrict__ K,
    const u16* __restrict__ Vt, u16* __restrict__ Ctx)
{
  __shared__ u16 plds[4][16][64];           // wave-private P tile (bf16)
  const int lane = threadIdx.x & 63;
  const int w = threadIdx.x >> 6;
  const int bx = blockIdx.x;
  const int qt = bx & 31;                   // 32 q-tiles of 64
  const int hh = (bx >> 5) % 12;
  const int bb = (bx >> 5) / 12;
  const int qb = qt * 64 + w * 16;          // this wave's q base
  const int lr = lane & 15;
  const int lk = (lane >> 4) << 3;
  const int orow = (lane >> 4) << 2;

  const u16* qp = Q  + (size_t)(bb * 2048 + qb) * 768 + hh * 64;
  const u16* kp = K  + (size_t)(bb * 2048) * 768 + hh * 64;
  const u16* vp = Vt + (size_t)((bb * 12 + hh) * 64) * 2048;

  const s8b qf0 = *(const s8b*)(qp + (size_t)lr * 768 + lk);
  const s8b qf1 = *(const s8b*)(qp + (size_t)lr * 768 + 32 + lk);

  const f4 fz = {0.f, 0.f, 0.f, 0.f};
  f4 oac[4];
  float mrow[4], lsum[4];
#pragma unroll
  for (int d = 0; d < 4; ++d) oac[d] = fz;
#pragma unroll
  for (int r = 0; r < 4; ++r) { mrow[r] = -1e30f; lsum[r] = 0.f; }

  const int tmax = (qb + 15) >> 6;
  for (int t = 0; t <= tmax; ++t) {
    const int kv0 = t << 6;
    // ---- S = Q K^T  (16 x 64), 4 j-subtiles
    f4 sf[4];
#pragma unroll
    for (int jt = 0; jt < 4; ++jt) {
      const u16* kr = kp + (size_t)(kv0 + jt * 16 + lr) * 768;
      s8b kb0 = *(const s8b*)(kr + lk);
      s8b kb1 = *(const s8b*)(kr + 32 + lk);
      f4 zz = fz;
      zz = __builtin_amdgcn_mfma_f32_16x16x32_bf16(qf0, kb0, zz, 0, 0, 0);
      zz = __builtin_amdgcn_mfma_f32_16x16x32_bf16(qf1, kb1, zz, 0, 0, 0);
      sf[jt] = zz;
    }
    // ---- causal mask (only on diagonal-straddling tiles)
    if (kv0 + 63 > qb) {
#pragma unroll
      for (int jt = 0; jt < 4; ++jt) {
        const int kvg = kv0 + jt * 16 + lr;
#pragma unroll
        for (int r = 0; r < 4; ++r)
          if (kvg > qb + orow + r) sf[jt][r] = -1e30f;
      }
    }
    // ---- online softmax
    float mnew[4], scl[4];
#pragma unroll
    for (int r = 0; r < 4; ++r) {
      float tm = fmaxf(fmaxf(sf[0][r], sf[1][r]), fmaxf(sf[2][r], sf[3][r]));
      tm = fmaxf(tm, __shfl_xor(tm, 1));
      tm = fmaxf(tm, __shfl_xor(tm, 2));
      tm = fmaxf(tm, __shfl_xor(tm, 4));
      tm = fmaxf(tm, __shfl_xor(tm, 8));
      mnew[r] = fmaxf(mrow[r], tm);
      scl[r] = __expf(mrow[r] - mnew[r]);
      mrow[r] = mnew[r];
    }
    float rs[4] = {0.f, 0.f, 0.f, 0.f};
#pragma unroll
    for (int jt = 0; jt < 4; ++jt)
#pragma unroll
      for (int r = 0; r < 4; ++r) {
        float p = __expf(sf[jt][r] - mnew[r]);
        sf[jt][r] = p;
        rs[r] += p;
      }
#pragma unroll
    for (int r = 0; r < 4; ++r) {
      float s = rs[r];
      s += __shfl_xor(s, 1);
      s += __shfl_xor(s, 2);
      s += __shfl_xor(s, 4);
      s += __shfl_xor(s, 8);
      lsum[r] = lsum[r] * scl[r] + s;
    }
#pragma unroll
    for (int d = 0; d < 4; ++d)
#pragma unroll
      for (int r = 0; r < 4; ++r) oac[d][r] *= scl[r];
    // ---- P -> LDS (acc layout -> row-major [16][64] bf16)
#pragma unroll
    for (int jt = 0; jt < 4; ++jt)
#pragma unroll
      for (int r = 0; r < 4; ++r)
        plds[w][orow + r][jt * 16 + lr] = f2bf(sf[jt][r]);
    // ---- O += P V  (A-frag from LDS, B-frag 16B contiguous from V^T)
#pragma unroll
    for (int kvc = 0; kvc < 2; ++kvc) {
      s8b pa = *(const s8b*)(&plds[w][lr][kvc * 32 + lk]);
#pragma unroll
      for (int d = 0; d < 4; ++d) {
        s8b vb = *(const s8b*)(vp + (size_t)(d * 16 + lr) * 2048 + kv0 + kvc * 32 + lk);
        oac[d] = __builtin_amdgcn_mfma_f32_16x16x32_bf16(pa, vb, oac[d], 0, 0, 0);
      }
    }
  }
  // ---- normalize + store ctx (bf16, [B,S,H*hw])
  u16* cp = Ctx + (size_t)(bb * 2048 + qb) * 768 + hh * 64;
  float inv[4];
#pragma unroll
  for (int r = 0; r < 4; ++r) inv[r] = 1.f / lsum[r];
#pragma unroll
  for (int d = 0; d < 4; ++d)
#pragma unroll
    for (int r = 0; r < 4; ++r)
      cp[(size_t)(orow + r) * 768 + d * 16 + lr] = f2bf(oac[d][r] * inv[r]);
}

// ---------------------------------------------------------------- output GEMM
// Out[m,n] = sum_k Ctx[m,k] * Wo[n,k] + bo[n]   (fp32 out)
__global__ __launch_bounds__(256) void out_gemm(
    const u16* __restrict__ A, const u16* __restrict__ W,
    const float* __restrict__ bias, float* __restrict__ Out)
{
  const int lane = threadIdx.x & 63;
  const int wid  = threadIdx.x >> 6;
  const int wr = wid >> 1, wc = wid & 1;
  const int mb = blockIdx.x * 128 + wr * 64;
  const int nb = blockIdx.y * 128 + wc * 64;
  const int lr = lane & 15;
  const int lk = (lane >> 4) << 3;

  const f4 fz = {0.f, 0.f, 0.f, 0.f};
  f4 acc[4][4];
#pragma unroll
  for (int i = 0; i < 4; ++i)
#pragma unroll
    for (int j = 0; j < 4; ++j) acc[i][j] = fz;

  const u16* a0 = A + (size_t)(mb + lr) * 768 + lk;
  const u16* b0 = W + (size_t)(nb + lr) * 768 + lk;

  for (int k0 = 0; k0 < 768; k0 += 32) {
    s8b af[4], bfr[4];
#pragma unroll
    for (int i = 0; i < 4; ++i) af[i]  = *(const s8b*)(a0 + (size_t)i * 16 * 768 + k0);
#pragma unroll
    for (int j = 0; j < 4; ++j) bfr[j] = *(const s8b*)(b0 + (size_t)j * 16 * 768 + k0);
#pragma unroll
    for (int i = 0; i < 4; ++i)
#pragma unroll
      for (int j = 0; j < 4; ++j)
        acc[i][j] = __builtin_amdgcn_mfma_f32_16x16x32_bf16(af[i], bfr[j], acc[i][j], 0, 0, 0);
  }

  const int orow = (lane >> 4) << 2;
#pragma unroll
  for (int j = 0; j < 4; ++j) {
    const int n = nb + j * 16 + lr;
    const float bn = bias[n];
#pragma unroll
    for (int i = 0; i < 4; ++i) {
      const int m0 = mb + i * 16 + orow;
#pragma unroll
      for (int r = 0; r < 4; ++r)
        Out[(size_t)(m0 + r) * 768 + n] = acc[i][j][r] + bn;
    }
  }
}

// ---------------------------------------------------------------- launch
extern "C" void kernel_launch(void* const* d_in, const int* in_sizes, int n_in,
                              void* d_out, int out_size, void* d_ws, size_t ws_size,
                              hipStream_t stream) {
  const float* emb = (const float*)d_in[0];
  const float* Wq  = (const float*)d_in[1];
  const float* Wk  = (const float*)d_in[2];
  const float* Wv  = (const float*)d_in[3];
  const float* Wo  = (const float*)d_in[4];
  const float* bo  = (const float*)d_in[5];

  char* ws = (char*)d_ws;
  const size_t SZ_X = (size_t)4096 * 768 * 2;   // 6,291,456
  const size_t SZ_W = (size_t)768 * 768 * 2;    // 1,179,648
  u16* Xb   = (u16*)(ws);
  u16* Wqb  = (u16*)(ws + SZ_X);
  u16* Wkb  = (u16*)(ws + SZ_X + SZ_W);
  u16* Wvb  = (u16*)(ws + SZ_X + 2 * SZ_W);
  u16* Wob  = (u16*)(ws + SZ_X + 3 * SZ_W);
  u16* Qb   = (u16*)(ws + SZ_X + 4 * SZ_W);
  u16* Kb   = (u16*)(ws + 2 * SZ_X + 4 * SZ_W);
  u16* Vtb  = (u16*)(ws + 3 * SZ_X + 4 * SZ_W);
  u16* Ctxb = (u16*)(ws + 4 * SZ_X + 4 * SZ_W);

  cvt_all<<<2048, 256, 0, stream>>>(emb, Wq, Wk, Wv, Wo, Xb, Wqb, Wkb, Wvb, Wob);
  qkv_gemm<<<dim3(32, 6, 3), 256, 0, stream>>>(Xb, Wqb, Wkb, Wvb, Qb, Kb, Vtb);
  attn_kernel<<<768, 256, 0, stream>>>(Qb, Kb, Vtb, Ctxb);
  out_gemm<<<dim3(32, 6), 256, 0, stream>>>(Ctxb, Wob, bo, (float*)d_out);
}

// Round 2
// 129.676 us; speedup vs baseline: 2.2305x; 2.2305x over previous
//
#include <hip/hip_runtime.h>

typedef unsigned short u16;
typedef unsigned int u32;
typedef short s8b __attribute__((ext_vector_type(8)));     // 8 x bf16 (raw shorts)
typedef float f4 __attribute__((ext_vector_type(4)));
typedef unsigned short u16x4 __attribute__((ext_vector_type(4)));
typedef float f32x4 __attribute__((ext_vector_type(4)));

__device__ __forceinline__ u16 f2bf(float f) {
  u32 u = __builtin_bit_cast(u32, f);
  u += 0x7fffu + ((u >> 16) & 1u);   // RNE
  return (u16)(u >> 16);
}

// async global->LDS, 16B per lane; lds dest = wave-uniform base + lane*16
__device__ __forceinline__ void gl_lds16(const u16* g, u16* l) {
  __builtin_amdgcn_global_load_lds(
      (const __attribute__((address_space(1))) u32*)g,
      (__attribute__((address_space(3))) u32*)l, 16, 0, 0);
}

// ---------------------------------------------------------------- convert
__global__ __launch_bounds__(256) void cvt_all(
    const float* __restrict__ e, const float* __restrict__ wq,
    const float* __restrict__ wk, const float* __restrict__ wv,
    const float* __restrict__ wo,
    u16* __restrict__ eo, u16* __restrict__ wqo, u16* __restrict__ wko,
    u16* __restrict__ wvo, u16* __restrict__ woo)
{
  const int EQ4 = 786432;
  const int WQ4 = 147456;
  const int TOT = EQ4 + 4 * WQ4;
  int i = blockIdx.x * 256 + threadIdx.x;
  const int stride = gridDim.x * 256;
  for (; i < TOT; i += stride) {
    const float* s; u16* d; int off;
    if (i < EQ4) { s = e; d = eo; off = i; }
    else {
      int j = i - EQ4; int w = j / WQ4; off = j - w * WQ4;
      s = (w == 0) ? wq : (w == 1) ? wk : (w == 2) ? wv : wo;
      d = (w == 0) ? wqo : (w == 1) ? wko : (w == 2) ? wvo : woo;
    }
    f32x4 v = ((const f32x4*)s)[off];
    u16x4 o = { f2bf(v[0]), f2bf(v[1]), f2bf(v[2]), f2bf(v[3]) };
    ((u16x4*)d)[off] = o;
  }
}

// ---------------------------------------------------------------- QKV GEMM
// 128x128 tile, BK=64, double-buffered LDS staged via global_load_lds,
// XOR-swizzled (chunk ^= row&7).  z: 0=Q(scaled) 1=K 2=V^T
__global__ __launch_bounds__(256) void qkv_gemm(
    const u16* __restrict__ X, const u16* __restrict__ Wq,
    const u16* __restrict__ Wk, const u16* __restrict__ Wv,
    u16* __restrict__ Qo, u16* __restrict__ Ko, u16* __restrict__ Vt)
{
  __shared__ u16 At[2][128][64];
  __shared__ u16 Bt[2][128][64];
  const int lane = threadIdx.x & 63;
  const int w    = threadIdx.x >> 6;
  const int wr = w >> 1, wc = w & 1;
  const int mb = blockIdx.x * 128;
  const int nb = blockIdx.y * 128;
  const int z  = blockIdx.z;
  const u16* W = (z == 0) ? Wq : (z == 1) ? Wk : Wv;

  const int lr = lane & 15;
  const int cl = lane >> 4;             // 0..3 (k-chunk base)
  const int srow = lane >> 3;           // staging: 0..7
  const int sx = (lane & 7) ^ srow;     // inverse-swizzled source chunk

  const f4 fz = {0.f, 0.f, 0.f, 0.f};
  f4 acc[4][4];
#pragma unroll
  for (int i = 0; i < 4; ++i)
#pragma unroll
    for (int j = 0; j < 4; ++j) acc[i][j] = fz;

  const u16* a0 = X + (size_t)mb * 768;
  const u16* b0 = W + (size_t)nb * 768;

#define QKV_STAGE(d, k0)                                                     \
  {                                                                          \
    _Pragma("unroll")                                                        \
    for (int s = 0; s < 4; ++s) {                                            \
      const int r0 = w * 32 + s * 8;                                         \
      gl_lds16(a0 + (size_t)(r0 + srow) * 768 + (k0) + sx * 8, &At[d][r0][0]); \
      gl_lds16(b0 + (size_t)(r0 + srow) * 768 + (k0) + sx * 8, &Bt[d][r0][0]); \
    }                                                                        \
  }

  QKV_STAGE(0, 0);
  __syncthreads();
  int db = 0;
  for (int t = 0; t < 12; ++t) {
    if (t < 11) QKV_STAGE(db ^ 1, (t + 1) * 64);
#pragma unroll
    for (int h = 0; h < 2; ++h) {
      s8b af[4], bf[4];
#pragma unroll
      for (int i = 0; i < 4; ++i) {
        const int rr = wr * 64 + i * 16 + lr;
        af[i] = *(const s8b*)&At[db][rr][((h * 4 + cl) ^ (rr & 7)) * 8];
      }
#pragma unroll
      for (int j = 0; j < 4; ++j) {
        const int rr = wc * 64 + j * 16 + lr;
        bf[j] = *(const s8b*)&Bt[db][rr][((h * 4 + cl) ^ (rr & 7)) * 8];
      }
#pragma unroll
      for (int i = 0; i < 4; ++i)
#pragma unroll
        for (int j = 0; j < 4; ++j)
          acc[i][j] = __builtin_amdgcn_mfma_f32_16x16x32_bf16(af[i], bf[j], acc[i][j], 0, 0, 0);
    }
    __syncthreads();
    db ^= 1;
  }

  const int mbase = mb + wr * 64;
  const int nbase = nb + wc * 64;
  const int orow = cl * 4;
  if (z == 2) {
#pragma unroll
    for (int i = 0; i < 4; ++i) {
      const int m0 = mbase + i * 16 + orow;
      const int bb = m0 >> 11, ss = m0 & 2047;
#pragma unroll
      for (int j = 0; j < 4; ++j) {
        const int n = nbase + j * 16 + lr;
        const int h = n >> 6, d = n & 63;
        u16x4 pk = { f2bf(acc[i][j][0]), f2bf(acc[i][j][1]),
                     f2bf(acc[i][j][2]), f2bf(acc[i][j][3]) };
        *(u16x4*)(Vt + (((size_t)(bb * 12 + h) * 64 + d) << 11) + ss) = pk;
      }
    }
  } else {
    u16* O = (z == 0) ? Qo : Ko;
    const float sc = (z == 0) ? 0.125f : 1.0f;
#pragma unroll
    for (int i = 0; i < 4; ++i) {
      const int m0 = mbase + i * 16 + orow;
#pragma unroll
      for (int j = 0; j < 4; ++j) {
        const int n = nbase + j * 16 + lr;
#pragma unroll
        for (int r = 0; r < 4; ++r)
          O[(size_t)(m0 + r) * 768 + n] = f2bf(acc[i][j][r] * sc);
      }
    }
  }
}

// ---------------------------------------------------------------- attention
// 4 waves/block, block = 64 q-rows; K/V tiles (64x64) double-buffered in LDS
// shared by all waves; balanced qt mapping so each CU's 3 blocks sum to ~49.5
// tiles of work.
__global__ __launch_bounds__(256) void attn_kernel(
    const u16* __restrict__ Q, const u16* __restrict__ K,
    const u16* __restrict__ Vt, u16* __restrict__ Ctx)
{
  __shared__ u16 kt[2][64][64];
  __shared__ u16 vt[2][64][64];
  __shared__ u16 pt[4][1024];           // per-wave [16][64], swizzled

  const int lane = threadIdx.x & 63;
  const int w = threadIdx.x >> 6;
  const int bx = blockIdx.x;
  const int g  = bx >> 8;               // 0..2
  const int i8 = bx & 255;
  const int q0 = i8 & 31;
  int qt;
  if (g == 0)      qt = q0;
  else if (g == 1) qt = (q0 + 16) & 31;
  else             qt = (q0 < 16) ? (31 - 2 * q0) : (62 - 2 * q0);
  const int bh = g * 8 + (i8 >> 5);
  const int bb = bh / 12, hh = bh - (bh / 12) * 12;

  const int qb = qt * 64 + w * 16;
  const int lr = lane & 15;
  const int cl = lane >> 4;
  const int lk = cl * 8;
  const int orow = cl * 4;
  const int srow = lane >> 3;
  const int sx = (lane & 7) ^ srow;

  const u16* qp = Q  + (size_t)(bb * 2048 + qb) * 768 + hh * 64;
  const u16* kp = K  + (size_t)(bb * 2048) * 768 + hh * 64;
  const u16* vp = Vt + (size_t)((bb * 12 + hh) * 64) * 2048;

  const s8b qf0 = *(const s8b*)(qp + (size_t)lr * 768 + lk);
  const s8b qf1 = *(const s8b*)(qp + (size_t)lr * 768 + 32 + lk);

  const f4 fz = {0.f, 0.f, 0.f, 0.f};
  f4 oac[4];
  float mrow[4], lsum[4];
#pragma unroll
  for (int d = 0; d < 4; ++d) oac[d] = fz;
#pragma unroll
  for (int r = 0; r < 4; ++r) { mrow[r] = -1e30f; lsum[r] = 0.f; }

#define ATTN_STAGE(d, kv0)                                                     \
  {                                                                            \
    const int r0 = w * 16;                                                     \
    gl_lds16(kp + (size_t)((kv0) + r0 + srow) * 768 + sx * 8, &kt[d][r0][0]);  \
    gl_lds16(kp + (size_t)((kv0) + r0 + 8 + srow) * 768 + sx * 8, &kt[d][r0 + 8][0]); \
    gl_lds16(vp + (size_t)(r0 + srow) * 2048 + (kv0) + sx * 8, &vt[d][r0][0]); \
    gl_lds16(vp + (size_t)(r0 + 8 + srow) * 2048 + (kv0) + sx * 8, &vt[d][r0 + 8][0]); \
  }

  ATTN_STAGE(0, 0);
  __syncthreads();
  int db = 0;
  for (int t = 0; t <= qt; ++t) {
    const int kv0 = t << 6;
    if (t < qt) ATTN_STAGE(db ^ 1, kv0 + 64);
    // ---- S = Q K^T (16x64)
    f4 sf[4];
#pragma unroll
    for (int jt = 0; jt < 4; ++jt) {
      const int rr = jt * 16 + lr;
      const int rx = rr & 7;
      s8b kb0 = *(const s8b*)&kt[db][rr][(cl ^ rx) * 8];
      s8b kb1 = *(const s8b*)&kt[db][rr][((4 + cl) ^ rx) * 8];
      f4 zz = fz;
      zz = __builtin_amdgcn_mfma_f32_16x16x32_bf16(qf0, kb0, zz, 0, 0, 0);
      zz = __builtin_amdgcn_mfma_f32_16x16x32_bf16(qf1, kb1, zz, 0, 0, 0);
      sf[jt] = zz;
    }
    // ---- causal mask (diagonal tile only; t==qt for every wave)
    if (t == qt) {
#pragma unroll
      for (int jt = 0; jt < 4; ++jt) {
        const int kvg = kv0 + jt * 16 + lr;
#pragma unroll
        for (int r = 0; r < 4; ++r)
          if (kvg > qb + orow + r) sf[jt][r] = -1e30f;
      }
    }
    // ---- online softmax
    float mnew[4], scl[4];
#pragma unroll
    for (int r = 0; r < 4; ++r) {
      float tm = fmaxf(fmaxf(sf[0][r], sf[1][r]), fmaxf(sf[2][r], sf[3][r]));
      tm = fmaxf(tm, __shfl_xor(tm, 1));
      tm = fmaxf(tm, __shfl_xor(tm, 2));
      tm = fmaxf(tm, __shfl_xor(tm, 4));
      tm = fmaxf(tm, __shfl_xor(tm, 8));
      mnew[r] = fmaxf(mrow[r], tm);
      scl[r] = __expf(mrow[r] - mnew[r]);
      mrow[r] = mnew[r];
    }
    float rs[4] = {0.f, 0.f, 0.f, 0.f};
#pragma unroll
    for (int jt = 0; jt < 4; ++jt)
#pragma unroll
      for (int r = 0; r < 4; ++r) {
        float p = __expf(sf[jt][r] - mnew[r]);
        sf[jt][r] = p;
        rs[r] += p;
      }
#pragma unroll
    for (int r = 0; r < 4; ++r) {
      float s = rs[r];
      s += __shfl_xor(s, 1);
      s += __shfl_xor(s, 2);
      s += __shfl_xor(s, 4);
      s += __shfl_xor(s, 8);
      lsum[r] = lsum[r] * scl[r] + s;
    }
#pragma unroll
    for (int d = 0; d < 4; ++d)
#pragma unroll
      for (int r = 0; r < 4; ++r) oac[d][r] *= scl[r];
    // ---- P -> LDS (swizzled)
#pragma unroll
    for (int jt = 0; jt < 4; ++jt)
#pragma unroll
      for (int r = 0; r < 4; ++r) {
        const int pr = orow + r;
        const int ch = (jt * 2 + (lr >> 3)) ^ (pr & 7);
        pt[w][pr * 64 + ch * 8 + (lr & 7)] = f2bf(sf[jt][r]);
      }
    // ---- O += P V
#pragma unroll
    for (int kvc = 0; kvc < 2; ++kvc) {
      s8b pa = *(const s8b*)&pt[w][lr * 64 + ((kvc * 4 + cl) ^ (lr & 7)) * 8];
#pragma unroll
      for (int dd = 0; dd < 4; ++dd) {
        const int rr = dd * 16 + lr;
        s8b vb = *(const s8b*)&vt[db][rr][((kvc * 4 + cl) ^ (rr & 7)) * 8];
        oac[dd] = __builtin_amdgcn_mfma_f32_16x16x32_bf16(pa, vb, oac[dd], 0, 0, 0);
      }
    }
    __syncthreads();
    db ^= 1;
  }
  // ---- normalize + store
  u16* cp = Ctx + (size_t)(bb * 2048 + qb) * 768 + hh * 64;
  float inv[4];
#pragma unroll
  for (int r = 0; r < 4; ++r) inv[r] = 1.f / lsum[r];
#pragma unroll
  for (int dd = 0; dd < 4; ++dd)
#pragma unroll
    for (int r = 0; r < 4; ++r)
      cp[(size_t)(orow + r) * 768 + dd * 16 + lr] = f2bf(oac[dd][r] * inv[r]);
}

// ---------------------------------------------------------------- output GEMM
// 64x64 tile (grid 768 = 3 blocks/CU), BK=64, dbuf LDS, swizzled.
__global__ __launch_bounds__(256) void out_gemm(
    const u16* __restrict__ A, const u16* __restrict__ W,
    const float* __restrict__ bias, float* __restrict__ Out)
{
  __shared__ u16 At[2][64][64];
  __shared__ u16 Bt[2][64][64];
  const int lane = threadIdx.x & 63;
  const int w    = threadIdx.x >> 6;
  const int wr = w >> 1, wc = w & 1;
  const int mb = blockIdx.x * 64;
  const int nb = blockIdx.y * 64;

  const int lr = lane & 15;
  const int cl = lane >> 4;
  const int srow = lane >> 3;
  const int sx = (lane & 7) ^ srow;

  const f4 fz = {0.f, 0.f, 0.f, 0.f};
  f4 acc[2][2];
#pragma unroll
  for (int i = 0; i < 2; ++i)
#pragma unroll
    for (int j = 0; j < 2; ++j) acc[i][j] = fz;

  const u16* a0 = A + (size_t)mb * 768;
  const u16* b0 = W + (size_t)nb * 768;

#define OUT_STAGE(d, k0)                                                     \
  {                                                                          \
    const int r0 = w * 16;                                                   \
    gl_lds16(a0 + (size_t)(r0 + srow) * 768 + (k0) + sx * 8, &At[d][r0][0]); \
    gl_lds16(a0 + (size_t)(r0 + 8 + srow) * 768 + (k0) + sx * 8, &At[d][r0 + 8][0]); \
    gl_lds16(b0 + (size_t)(r0 + srow) * 768 + (k0) + sx * 8, &Bt[d][r0][0]); \
    gl_lds16(b0 + (size_t)(r0 + 8 + srow) * 768 + (k0) + sx * 8, &Bt[d][r0 + 8][0]); \
  }

  OUT_STAGE(0, 0);
  __syncthreads();
  int db = 0;
  for (int t = 0; t < 12; ++t) {
    if (t < 11) OUT_STAGE(db ^ 1, (t + 1) * 64);
#pragma unroll
    for (int h = 0; h < 2; ++h) {
      s8b af[2], bf[2];
#pragma unroll
      for (int i = 0; i < 2; ++i) {
        const int rr = wr * 32 + i * 16 + lr;
        af[i] = *(const s8b*)&At[db][rr][((h * 4 + cl) ^ (rr & 7)) * 8];
      }
#pragma unroll
      for (int j = 0; j < 2; ++j) {
        const int rr = wc * 32 + j * 16 + lr;
        bf[j] = *(const s8b*)&Bt[db][rr][((h * 4 + cl) ^ (rr & 7)) * 8];
      }
#pragma unroll
      for (int i = 0; i < 2; ++i)
#pragma unroll
        for (int j = 0; j < 2; ++j)
          acc[i][j] = __builtin_amdgcn_mfma_f32_16x16x32_bf16(af[i], bf[j], acc[i][j], 0, 0, 0);
    }
    __syncthreads();
    db ^= 1;
  }

  const int orow = cl * 4;
#pragma unroll
  for (int j = 0; j < 2; ++j) {
    const int n = nb + wc * 32 + j * 16 + lr;
    const float bn = bias[n];
#pragma unroll
    for (int i = 0; i < 2; ++i) {
      const int m0 = mb + wr * 32 + i * 16 + orow;
#pragma unroll
      for (int r = 0; r < 4; ++r)
        Out[(size_t)(m0 + r) * 768 + n] = acc[i][j][r] + bn;
    }
  }
}

// ---------------------------------------------------------------- launch
extern "C" void kernel_launch(void* const* d_in, const int* in_sizes, int n_in,
                              void* d_out, int out_size, void* d_ws, size_t ws_size,
                              hipStream_t stream) {
  const float* emb = (const float*)d_in[0];
  const float* Wq  = (const float*)d_in[1];
  const float* Wk  = (const float*)d_in[2];
  const float* Wv  = (const float*)d_in[3];
  const float* Wo  = (const float*)d_in[4];
  const float* bo  = (const float*)d_in[5];

  char* ws = (char*)d_ws;
  const size_t SZ_X = (size_t)4096 * 768 * 2;
  const size_t SZ_W = (size_t)768 * 768 * 2;
  u16* Xb   = (u16*)(ws);
  u16* Wqb  = (u16*)(ws + SZ_X);
  u16* Wkb  = (u16*)(ws + SZ_X + SZ_W);
  u16* Wvb  = (u16*)(ws + SZ_X + 2 * SZ_W);
  u16* Wob  = (u16*)(ws + SZ_X + 3 * SZ_W);
  u16* Qb   = (u16*)(ws + SZ_X + 4 * SZ_W);
  u16* Kb   = (u16*)(ws + 2 * SZ_X + 4 * SZ_W);
  u16* Vtb  = (u16*)(ws + 3 * SZ_X + 4 * SZ_W);
  u16* Ctxb = (u16*)(ws + 4 * SZ_X + 4 * SZ_W);

  cvt_all<<<2048, 256, 0, stream>>>(emb, Wq, Wk, Wv, Wo, Xb, Wqb, Wkb, Wvb, Wob);
  qkv_gemm<<<dim3(32, 6, 3), 256, 0, stream>>>(Xb, Wqb, Wkb, Wvb, Qb, Kb, Vtb);
  attn_kernel<<<768, 256, 0, stream>>>(Qb, Kb, Vtb, Ctxb);
  out_gemm<<<dim3(64, 12), 256, 0, stream>>>(Ctxb, Wob, bo, (float*)d_out);
}

// Round 3
// 115.838 us; speedup vs baseline: 2.4970x; 1.1195x over previous
//
#include <hip/hip_runtime.h>
#include <math.h>

typedef unsigned short u16;
typedef unsigned int u32;
typedef short s8b __attribute__((ext_vector_type(8)));     // 8 x bf16 (raw shorts)
typedef float f4 __attribute__((ext_vector_type(4)));
typedef float f16v __attribute__((ext_vector_type(16)));
typedef unsigned short u16x4 __attribute__((ext_vector_type(4)));
typedef unsigned int u32x4 __attribute__((ext_vector_type(4)));
typedef float f32x4 __attribute__((ext_vector_type(4)));

// fold 1/sqrt(64) * log2(e) into Q so softmax uses exp2 directly
#define SCALE_Q 0.18033688011112042f

__device__ __forceinline__ u16 f2bf(float f) {
  u32 u = __builtin_bit_cast(u32, f);
  u += 0x7fffu + ((u >> 16) & 1u);   // RNE
  return (u16)(u >> 16);
}

// async global->LDS, 16B per lane; lds dest = wave-uniform base + lane*16
__device__ __forceinline__ void gl_lds16(const u16* g, u16* l) {
  __builtin_amdgcn_global_load_lds(
      (const __attribute__((address_space(1))) u32*)g,
      (__attribute__((address_space(3))) u32*)l, 16, 0, 0);
}

__device__ __forceinline__ u32 cvtpk_bf16(float lo, float hi) {
  u32 r;
  asm volatile("v_cvt_pk_bf16_f32 %0, %1, %2" : "=v"(r) : "v"(lo), "v"(hi));
  return r;
}

__device__ __forceinline__ void plswap(u32& a, u32& b) {
  asm volatile("v_permlane32_swap_b32 %0, %1" : "+v"(a), "+v"(b));
}

// ---------------------------------------------------------------- convert
__global__ __launch_bounds__(256) void cvt_all(
    const float* __restrict__ e, const float* __restrict__ wq,
    const float* __restrict__ wk, const float* __restrict__ wv,
    const float* __restrict__ wo,
    u16* __restrict__ eo, u16* __restrict__ wqo, u16* __restrict__ wko,
    u16* __restrict__ wvo, u16* __restrict__ woo)
{
  const int EQ4 = 786432;
  const int WQ4 = 147456;
  const int TOT = EQ4 + 4 * WQ4;
  int i = blockIdx.x * 256 + threadIdx.x;
  const int stride = gridDim.x * 256;
  for (; i < TOT; i += stride) {
    const float* s; u16* d; int off;
    if (i < EQ4) { s = e; d = eo; off = i; }
    else {
      int j = i - EQ4; int w = j / WQ4; off = j - w * WQ4;
      s = (w == 0) ? wq : (w == 1) ? wk : (w == 2) ? wv : wo;
      d = (w == 0) ? wqo : (w == 1) ? wko : (w == 2) ? wvo : woo;
    }
    f32x4 v = ((const f32x4*)s)[off];
    u16x4 o = { f2bf(v[0]), f2bf(v[1]), f2bf(v[2]), f2bf(v[3]) };
    ((u16x4*)d)[off] = o;
  }
}

// ---------------------------------------------------------------- QKV GEMM
// (unchanged from round 2 except Q scale now folds log2e)
__global__ __launch_bounds__(256) void qkv_gemm(
    const u16* __restrict__ X, const u16* __restrict__ Wq,
    const u16* __restrict__ Wk, const u16* __restrict__ Wv,
    u16* __restrict__ Qo, u16* __restrict__ Ko, u16* __restrict__ Vt)
{
  __shared__ u16 At[2][128][64];
  __shared__ u16 Bt[2][128][64];
  const int lane = threadIdx.x & 63;
  const int w    = threadIdx.x >> 6;
  const int wr = w >> 1, wc = w & 1;
  const int mb = blockIdx.x * 128;
  const int nb = blockIdx.y * 128;
  const int z  = blockIdx.z;
  const u16* W = (z == 0) ? Wq : (z == 1) ? Wk : Wv;

  const int lr = lane & 15;
  const int cl = lane >> 4;
  const int srow = lane >> 3;
  const int sx = (lane & 7) ^ srow;

  const f4 fz = {0.f, 0.f, 0.f, 0.f};
  f4 acc[4][4];
#pragma unroll
  for (int i = 0; i < 4; ++i)
#pragma unroll
    for (int j = 0; j < 4; ++j) acc[i][j] = fz;

  const u16* a0 = X + (size_t)mb * 768;
  const u16* b0 = W + (size_t)nb * 768;

#define QKV_STAGE(d, k0)                                                     \
  {                                                                          \
    _Pragma("unroll")                                                        \
    for (int s = 0; s < 4; ++s) {                                            \
      const int r0 = w * 32 + s * 8;                                         \
      gl_lds16(a0 + (size_t)(r0 + srow) * 768 + (k0) + sx * 8, &At[d][r0][0]); \
      gl_lds16(b0 + (size_t)(r0 + srow) * 768 + (k0) + sx * 8, &Bt[d][r0][0]); \
    }                                                                        \
  }

  QKV_STAGE(0, 0);
  __syncthreads();
  int db = 0;
  for (int t = 0; t < 12; ++t) {
    if (t < 11) QKV_STAGE(db ^ 1, (t + 1) * 64);
#pragma unroll
    for (int h = 0; h < 2; ++h) {
      s8b af[4], bf[4];
#pragma unroll
      for (int i = 0; i < 4; ++i) {
        const int rr = wr * 64 + i * 16 + lr;
        af[i] = *(const s8b*)&At[db][rr][((h * 4 + cl) ^ (rr & 7)) * 8];
      }
#pragma unroll
      for (int j = 0; j < 4; ++j) {
        const int rr = wc * 64 + j * 16 + lr;
        bf[j] = *(const s8b*)&Bt[db][rr][((h * 4 + cl) ^ (rr & 7)) * 8];
      }
#pragma unroll
      for (int i = 0; i < 4; ++i)
#pragma unroll
        for (int j = 0; j < 4; ++j)
          acc[i][j] = __builtin_amdgcn_mfma_f32_16x16x32_bf16(af[i], bf[j], acc[i][j], 0, 0, 0);
    }
    __syncthreads();
    db ^= 1;
  }

  const int mbase = mb + wr * 64;
  const int nbase = nb + wc * 64;
  const int orow = cl * 4;
  if (z == 2) {
#pragma unroll
    for (int i = 0; i < 4; ++i) {
      const int m0 = mbase + i * 16 + orow;
      const int bb = m0 >> 11, ss = m0 & 2047;
#pragma unroll
      for (int j = 0; j < 4; ++j) {
        const int n = nbase + j * 16 + lr;
        const int h = n >> 6, d = n & 63;
        u16x4 pk = { f2bf(acc[i][j][0]), f2bf(acc[i][j][1]),
                     f2bf(acc[i][j][2]), f2bf(acc[i][j][3]) };
        *(u16x4*)(Vt + (((size_t)(bb * 12 + h) * 64 + d) << 11) + ss) = pk;
      }
    }
  } else {
    u16* O = (z == 0) ? Qo : Ko;
    const float sc = (z == 0) ? SCALE_Q : 1.0f;
#pragma unroll
    for (int i = 0; i < 4; ++i) {
      const int m0 = mbase + i * 16 + orow;
#pragma unroll
      for (int j = 0; j < 4; ++j) {
        const int n = nbase + j * 16 + lr;
#pragma unroll
        for (int r = 0; r < 4; ++r)
          O[(size_t)(m0 + r) * 768 + n] = f2bf(acc[i][j][r] * sc);
      }
    }
  }
}

// ---------------------------------------------------------------- attention
// 2 waves/block x 32 q-rows; 32x32x16 MFMA; swapped QK^T -> in-register
// softmax (no max subtraction: exp2 of pre-scaled S, exact algebraic
// equivalence); P->A-frag via cvt_pk + permlane32_swap; l via ones-MFMA.
__global__ __launch_bounds__(128) void attn_kernel(
    const u16* __restrict__ Q, const u16* __restrict__ K,
    const u16* __restrict__ Vt, u16* __restrict__ Ctx)
{
  __shared__ u16 kt[2][64][64];
  __shared__ u16 vt[2][64][64];

  const int lane = threadIdx.x & 63;
  const int w = threadIdx.x >> 6;          // 0..1
  const int bx = blockIdx.x;
  const int g  = bx >> 8;                  // 0..2  (balanced qt mapping)
  const int i8 = bx & 255;
  const int q0 = i8 & 31;
  int qt;
  if (g == 0)      qt = q0;
  else if (g == 1) qt = (q0 + 16) & 31;
  else             qt = (q0 < 16) ? (31 - 2 * q0) : (62 - 2 * q0);
  const int bh = g * 8 + (i8 >> 5);
  const int bb = bh / 12, hh = bh - (bh / 12) * 12;

  const int qb  = qt * 64;
  const int qw0 = qb + w * 32;             // this wave's q base
  const int l31 = lane & 31;
  const int hi  = lane >> 5;               // 0..1
  const int r7  = l31 & 7;
  const int srow = lane >> 3;
  const int sx = (lane & 7) ^ (srow & 7);

  const u16* qp = Q  + (size_t)(bb * 2048) * 768 + hh * 64;
  const u16* kp = K  + (size_t)(bb * 2048) * 768 + hh * 64;
  const u16* vp = Vt + (size_t)((bb * 12 + hh) * 64) * 2048;

  // Q fragments: B-operand, n = qw0+l31, k = ks*16 + hi*8 + e
  const u16* qrow = qp + (size_t)(qw0 + l31) * 768;
  s8b qf[4];
#pragma unroll
  for (int ks = 0; ks < 4; ++ks)
    qf[ks] = *(const s8b*)(qrow + ks * 16 + hi * 8);

  s8b onesf;
#pragma unroll
  for (int i = 0; i < 8; ++i) onesf[i] = (short)0x3F80;   // bf16 1.0

  const f16v z16 = {0.f,0.f,0.f,0.f,0.f,0.f,0.f,0.f,
                    0.f,0.f,0.f,0.f,0.f,0.f,0.f,0.f};
  f16v oac0 = z16, oac1 = z16, lacc = z16;

  // staging: wave w stages K rows w*32..w*32+31 and V rows w*32..w*32+31
#define ATTN_STAGE(d, kv0)                                                     \
  {                                                                            \
    const int r0 = w * 32;                                                     \
    _Pragma("unroll")                                                          \
    for (int s = 0; s < 4; ++s) {                                              \
      gl_lds16(kp + (size_t)((kv0) + r0 + s * 8 + srow) * 768 + sx * 8,        \
               &kt[d][r0 + s * 8][0]);                                         \
      gl_lds16(vp + (size_t)(r0 + s * 8 + srow) * 2048 + (kv0) + sx * 8,       \
               &vt[d][r0 + s * 8][0]);                                         \
    }                                                                          \
  }

  ATTN_STAGE(0, 0);
  __syncthreads();
  int db = 0;
  for (int t = 0; t <= qt; ++t) {
    const int kv0 = t << 6;
    if (t < qt) ATTN_STAGE(db ^ 1, kv0 + 64);
    const bool diag = (t == qt);
    const bool domt1 = !(diag && w == 0);   // w=0 diagonal: mt1 fully masked

    // ---- S^T = K * Q^T  (A = K rows, B = Q rows)
    f16v st0 = z16, st1 = z16;
    __builtin_amdgcn_s_setprio(1);
#pragma unroll
    for (int ks = 0; ks < 4; ++ks) {
      const int row0 = l31;
      s8b kf0 = *(const s8b*)&kt[db][row0][(((ks * 2 + hi) ^ r7) * 8)];
      st0 = __builtin_amdgcn_mfma_f32_32x32x16_bf16(kf0, qf[ks], st0, 0, 0, 0);
    }
    if (domt1) {
#pragma unroll
      for (int ks = 0; ks < 4; ++ks) {
        const int row1 = 32 + l31;
        s8b kf1 = *(const s8b*)&kt[db][row1][(((ks * 2 + hi) ^ r7) * 8)];
        st1 = __builtin_amdgcn_mfma_f32_32x32x16_bf16(kf1, qf[ks], st1, 0, 0, 0);
      }
    }
    __builtin_amdgcn_s_setprio(0);

    // ---- P = exp2(S'), causal mask on diagonal tile
    const int qg = qw0 + l31;
    float p0[16], p1[16];
    if (diag) {
#pragma unroll
      for (int r = 0; r < 16; ++r) {
        const int kvl = (r & 3) + 8 * (r >> 2) + 4 * hi;
        p0[r] = (kv0 + kvl <= qg) ? exp2f(st0[r]) : 0.f;
      }
      if (domt1) {
#pragma unroll
        for (int r = 0; r < 16; ++r) {
          const int kvl = 32 + (r & 3) + 8 * (r >> 2) + 4 * hi;
          p1[r] = (kv0 + kvl <= qg) ? exp2f(st1[r]) : 0.f;
        }
      }
    } else {
#pragma unroll
      for (int r = 0; r < 16; ++r) p0[r] = exp2f(st0[r]);
#pragma unroll
      for (int r = 0; r < 16; ++r) p1[r] = exp2f(st1[r]);
    }

    // ---- pack P -> A-frags (cvt_pk + permlane32_swap), PV + l MFMAs
#pragma unroll
    for (int mt = 0; mt < 2; ++mt) {
      if (mt == 1 && !domt1) break;
      const float* pp = (mt == 0) ? p0 : p1;
      u32 pk0 = cvtpk_bf16(pp[0],  pp[1]);
      u32 pk1 = cvtpk_bf16(pp[2],  pp[3]);
      u32 pk2 = cvtpk_bf16(pp[4],  pp[5]);
      u32 pk3 = cvtpk_bf16(pp[6],  pp[7]);
      u32 pk4 = cvtpk_bf16(pp[8],  pp[9]);
      u32 pk5 = cvtpk_bf16(pp[10], pp[11]);
      u32 pk6 = cvtpk_bf16(pp[12], pp[13]);
      u32 pk7 = cvtpk_bf16(pp[14], pp[15]);
      plswap(pk0, pk2);
      plswap(pk1, pk3);
      plswap(pk4, pk6);
      plswap(pk5, pk7);
      u32x4 w0 = { pk0, pk1, pk2, pk3 };   // k-slot: kv mt*32 + 0..15
      u32x4 w1 = { pk4, pk5, pk6, pk7 };   // k-slot: kv mt*32 + 16..31
      s8b pa0 = __builtin_bit_cast(s8b, w0);
      s8b pa1 = __builtin_bit_cast(s8b, w1);

      const int rn0 = l31, rn1 = 32 + l31;
      const int c00 = ((mt * 4 + 0 + hi) ^ (rn0 & 7)) * 8;
      const int c01 = ((mt * 4 + 2 + hi) ^ (rn0 & 7)) * 8;
      const int c10 = ((mt * 4 + 0 + hi) ^ (rn1 & 7)) * 8;
      const int c11 = ((mt * 4 + 2 + hi) ^ (rn1 & 7)) * 8;
      s8b v00 = *(const s8b*)&vt[db][rn0][c00];
      s8b v01 = *(const s8b*)&vt[db][rn0][c01];
      s8b v10 = *(const s8b*)&vt[db][rn1][c10];
      s8b v11 = *(const s8b*)&vt[db][rn1][c11];
      __builtin_amdgcn_s_setprio(1);
      oac0 = __builtin_amdgcn_mfma_f32_32x32x16_bf16(pa0, v00, oac0, 0, 0, 0);
      oac0 = __builtin_amdgcn_mfma_f32_32x32x16_bf16(pa1, v01, oac0, 0, 0, 0);
      oac1 = __builtin_amdgcn_mfma_f32_32x32x16_bf16(pa0, v10, oac1, 0, 0, 0);
      oac1 = __builtin_amdgcn_mfma_f32_32x32x16_bf16(pa1, v11, oac1, 0, 0, 0);
      lacc = __builtin_amdgcn_mfma_f32_32x32x16_bf16(pa0, onesf, lacc, 0, 0, 0);
      lacc = __builtin_amdgcn_mfma_f32_32x32x16_bf16(pa1, onesf, lacc, 0, 0, 0);
      __builtin_amdgcn_s_setprio(0);
    }

    __syncthreads();
    db ^= 1;
  }

  // ---- normalize + store ctx: lacc rows match oac rows exactly
  u16* cp = Ctx + ((size_t)(bb * 2048) * 768) + hh * 64;
  float inv[16];
#pragma unroll
  for (int r = 0; r < 16; ++r) inv[r] = 1.0f / lacc[r];
#pragma unroll
  for (int r = 0; r < 16; ++r) {
    const int row = qw0 + (r & 3) + 8 * (r >> 2) + 4 * hi;
    cp[(size_t)row * 768 + l31]      = f2bf(oac0[r] * inv[r]);
    cp[(size_t)row * 768 + 32 + l31] = f2bf(oac1[r] * inv[r]);
  }
}

// ---------------------------------------------------------------- output GEMM
__global__ __launch_bounds__(256) void out_gemm(
    const u16* __restrict__ A, const u16* __restrict__ W,
    const float* __restrict__ bias, float* __restrict__ Out)
{
  __shared__ u16 At[2][64][64];
  __shared__ u16 Bt[2][64][64];
  const int lane = threadIdx.x & 63;
  const int w    = threadIdx.x >> 6;
  const int wr = w >> 1, wc = w & 1;
  const int mb = blockIdx.x * 64;
  const int nb = blockIdx.y * 64;

  const int lr = lane & 15;
  const int cl = lane >> 4;
  const int srow = lane >> 3;
  const int sx = (lane & 7) ^ srow;

  const f4 fz = {0.f, 0.f, 0.f, 0.f};
  f4 acc[2][2];
#pragma unroll
  for (int i = 0; i < 2; ++i)
#pragma unroll
    for (int j = 0; j < 2; ++j) acc[i][j] = fz;

  const u16* a0 = A + (size_t)mb * 768;
  const u16* b0 = W + (size_t)nb * 768;

#define OUT_STAGE(d, k0)                                                     \
  {                                                                          \
    const int r0 = w * 16;                                                   \
    gl_lds16(a0 + (size_t)(r0 + srow) * 768 + (k0) + sx * 8, &At[d][r0][0]); \
    gl_lds16(a0 + (size_t)(r0 + 8 + srow) * 768 + (k0) + sx * 8, &At[d][r0 + 8][0]); \
    gl_lds16(b0 + (size_t)(r0 + srow) * 768 + (k0) + sx * 8, &Bt[d][r0][0]); \
    gl_lds16(b0 + (size_t)(r0 + 8 + srow) * 768 + (k0) + sx * 8, &Bt[d][r0 + 8][0]); \
  }

  OUT_STAGE(0, 0);
  __syncthreads();
  int db = 0;
  for (int t = 0; t < 12; ++t) {
    if (t < 11) OUT_STAGE(db ^ 1, (t + 1) * 64);
#pragma unroll
    for (int h = 0; h < 2; ++h) {
      s8b af[2], bf[2];
#pragma unroll
      for (int i = 0; i < 2; ++i) {
        const int rr = wr * 32 + i * 16 + lr;
        af[i] = *(const s8b*)&At[db][rr][((h * 4 + cl) ^ (rr & 7)) * 8];
      }
#pragma unroll
      for (int j = 0; j < 2; ++j) {
        const int rr = wc * 32 + j * 16 + lr;
        bf[j] = *(const s8b*)&Bt[db][rr][((h * 4 + cl) ^ (rr & 7)) * 8];
      }
#pragma unroll
      for (int i = 0; i < 2; ++i)
#pragma unroll
        for (int j = 0; j < 2; ++j)
          acc[i][j] = __builtin_amdgcn_mfma_f32_16x16x32_bf16(af[i], bf[j], acc[i][j], 0, 0, 0);
    }
    __syncthreads();
    db ^= 1;
  }

  const int orow = cl * 4;
#pragma unroll
  for (int j = 0; j < 2; ++j) {
    const int n = nb + wc * 32 + j * 16 + lr;
    const float bn = bias[n];
#pragma unroll
    for (int i = 0; i < 2; ++i) {
      const int m0 = mb + wr * 32 + i * 16 + orow;
#pragma unroll
      for (int r = 0; r < 4; ++r)
        Out[(size_t)(m0 + r) * 768 + n] = acc[i][j][r] + bn;
    }
  }
}

// ---------------------------------------------------------------- launch
extern "C" void kernel_launch(void* const* d_in, const int* in_sizes, int n_in,
                              void* d_out, int out_size, void* d_ws, size_t ws_size,
                              hipStream_t stream) {
  const float* emb = (const float*)d_in[0];
  const float* Wq  = (const float*)d_in[1];
  const float* Wk  = (const float*)d_in[2];
  const float* Wv  = (const float*)d_in[3];
  const float* Wo  = (const float*)d_in[4];
  const float* bo  = (const float*)d_in[5];

  char* ws = (char*)d_ws;
  const size_t SZ_X = (size_t)4096 * 768 * 2;
  const size_t SZ_W = (size_t)768 * 768 * 2;
  u16* Xb   = (u16*)(ws);
  u16* Wqb  = (u16*)(ws + SZ_X);
  u16* Wkb  = (u16*)(ws + SZ_X + SZ_W);
  u16* Wvb  = (u16*)(ws + SZ_X + 2 * SZ_W);
  u16* Wob  = (u16*)(ws + SZ_X + 3 * SZ_W);
  u16* Qb   = (u16*)(ws + SZ_X + 4 * SZ_W);
  u16* Kb   = (u16*)(ws + 2 * SZ_X + 4 * SZ_W);
  u16* Vtb  = (u16*)(ws + 3 * SZ_X + 4 * SZ_W);
  u16* Ctxb = (u16*)(ws + 4 * SZ_X + 4 * SZ_W);

  cvt_all<<<2048, 256, 0, stream>>>(emb, Wq, Wk, Wv, Wo, Xb, Wqb, Wkb, Wvb, Wob);
  qkv_gemm<<<dim3(32, 6, 3), 256, 0, stream>>>(Xb, Wqb, Wkb, Wvb, Qb, Kb, Vtb);
  attn_kernel<<<768, 128, 0, stream>>>(Qb, Kb, Vtb, Ctxb);
  out_gemm<<<dim3(64, 12), 256, 0, stream>>>(Ctxb, Wob, bo, (float*)d_out);
}

// Round 4
// 100.898 us; speedup vs baseline: 2.8667x; 1.1481x over previous
//
#include <hip/hip_runtime.h>
#include <math.h>

typedef unsigned short u16;
typedef unsigned int u32;
typedef short s8b __attribute__((ext_vector_type(8)));     // 8 x bf16 (raw shorts)
typedef float f4 __attribute__((ext_vector_type(4)));
typedef float f16v __attribute__((ext_vector_type(16)));
typedef unsigned short u16x4 __attribute__((ext_vector_type(4)));
typedef unsigned int u32x4 __attribute__((ext_vector_type(4)));
typedef float f32x4 __attribute__((ext_vector_type(4)));

// fold 1/sqrt(64) * log2(e) into Q so softmax uses exp2 directly
#define SCALE_Q 0.18033688011112042f

__device__ __forceinline__ u16 f2bf(float f) {
  u32 u = __builtin_bit_cast(u32, f);
  u += 0x7fffu + ((u >> 16) & 1u);   // RNE
  return (u16)(u >> 16);
}

// async global->LDS, 16B per lane; lds dest = wave-uniform base + lane*16
__device__ __forceinline__ void gl_lds16(const u16* g, u16* l) {
  __builtin_amdgcn_global_load_lds(
      (const __attribute__((address_space(1))) u32*)g,
      (__attribute__((address_space(3))) u32*)l, 16, 0, 0);
}

__device__ __forceinline__ u32 cvtpk_bf16(float lo, float hi) {
  u32 r;
  asm volatile("v_cvt_pk_bf16_f32 %0, %1, %2" : "=v"(r) : "v"(lo), "v"(hi));
  return r;
}

__device__ __forceinline__ void plswap(u32& a, u32& b) {
  asm volatile("v_permlane32_swap_b32 %0, %1" : "+v"(a), "+v"(b));
}

// ---------------------------------------------------------------- convert
__global__ __launch_bounds__(256) void cvt_all(
    const float* __restrict__ e, const float* __restrict__ wq,
    const float* __restrict__ wk, const float* __restrict__ wv,
    const float* __restrict__ wo,
    u16* __restrict__ eo, u16* __restrict__ wqo, u16* __restrict__ wko,
    u16* __restrict__ wvo, u16* __restrict__ woo)
{
  const int EQ4 = 786432;
  const int WQ4 = 147456;
  const int TOT = EQ4 + 4 * WQ4;
  int i = blockIdx.x * 256 + threadIdx.x;
  const int stride = gridDim.x * 256;
  for (; i < TOT; i += stride) {
    const float* s; u16* d; int off;
    if (i < EQ4) { s = e; d = eo; off = i; }
    else {
      int j = i - EQ4; int w = j / WQ4; off = j - w * WQ4;
      s = (w == 0) ? wq : (w == 1) ? wk : (w == 2) ? wv : wo;
      d = (w == 0) ? wqo : (w == 1) ? wko : (w == 2) ? wvo : woo;
    }
    f32x4 v = ((const f32x4*)s)[off];
    u16x4 o = { f2bf(v[0]), f2bf(v[1]), f2bf(v[2]), f2bf(v[3]) };
    ((u16x4*)d)[off] = o;
  }
}

// ---------------------------------------------------------------- QKV GEMM
// 128x96 tile, BK=32, grid (32,8,3)=768 = exactly 3 blocks/CU.
// LDS 28KB dbuf, XOR-swizzle chunk^=(row&3).  z: 0=Q(scaled) 1=K 2=V^T
__global__ __launch_bounds__(256) void qkv_gemm(
    const u16* __restrict__ X, const u16* __restrict__ Wq,
    const u16* __restrict__ Wk, const u16* __restrict__ Wv,
    u16* __restrict__ Qo, u16* __restrict__ Ko, u16* __restrict__ Vt)
{
  __shared__ u16 At[2][128][32];
  __shared__ u16 Bt[2][96][32];
  const int lane = threadIdx.x & 63;
  const int w    = threadIdx.x >> 6;
  const int wr = w >> 1, wc = w & 1;
  const int mb = blockIdx.x * 128;
  const int nb = blockIdx.y * 96;
  const int z  = blockIdx.z;
  const u16* W = (z == 0) ? Wq : (z == 1) ? Wk : Wv;

  const int lr = lane & 15;
  const int cl = lane >> 4;             // k-chunk 0..3
  const int srow = lane >> 2;           // staging row 0..15
  const int sx = (lane & 3) ^ (srow & 3);

  const f4 fz = {0.f, 0.f, 0.f, 0.f};
  f4 acc[4][3];
#pragma unroll
  for (int i = 0; i < 4; ++i)
#pragma unroll
    for (int j = 0; j < 3; ++j) acc[i][j] = fz;

  const u16* a0 = X + (size_t)mb * 768;
  const u16* b0 = W + (size_t)nb * 768;

#define QKV_STAGE(d, k0)                                                       \
  {                                                                            \
    gl_lds16(a0 + (size_t)(w * 32 + srow) * 768 + (k0) + sx * 8,               \
             &At[d][w * 32][0]);                                               \
    gl_lds16(a0 + (size_t)(w * 32 + 16 + srow) * 768 + (k0) + sx * 8,          \
             &At[d][w * 32 + 16][0]);                                          \
    if (w < 3) {                                                               \
      gl_lds16(b0 + (size_t)(w * 32 + srow) * 768 + (k0) + sx * 8,             \
               &Bt[d][w * 32][0]);                                             \
      gl_lds16(b0 + (size_t)(w * 32 + 16 + srow) * 768 + (k0) + sx * 8,        \
               &Bt[d][w * 32 + 16][0]);                                        \
    }                                                                          \
  }

  QKV_STAGE(0, 0);
  __syncthreads();
  int db = 0;
  for (int t = 0; t < 24; ++t) {
    if (t < 23) QKV_STAGE(db ^ 1, (t + 1) * 32);
    s8b af[4], bf[3];
#pragma unroll
    for (int i = 0; i < 4; ++i) {
      const int rr = wr * 64 + i * 16 + lr;
      af[i] = *(const s8b*)&At[db][rr][(cl ^ (rr & 3)) * 8];
    }
#pragma unroll
    for (int j = 0; j < 3; ++j) {
      const int rr = wc * 48 + j * 16 + lr;
      bf[j] = *(const s8b*)&Bt[db][rr][(cl ^ (rr & 3)) * 8];
    }
#pragma unroll
    for (int i = 0; i < 4; ++i)
#pragma unroll
      for (int j = 0; j < 3; ++j)
        acc[i][j] = __builtin_amdgcn_mfma_f32_16x16x32_bf16(af[i], bf[j], acc[i][j], 0, 0, 0);
    __syncthreads();
    db ^= 1;
  }

  const int mbase = mb + wr * 64;
  const int nbase = nb + wc * 48;
  const int orow = cl * 4;
  if (z == 2) {
#pragma unroll
    for (int i = 0; i < 4; ++i) {
      const int m0 = mbase + i * 16 + orow;
      const int bb = m0 >> 11, ss = m0 & 2047;
#pragma unroll
      for (int j = 0; j < 3; ++j) {
        const int n = nbase + j * 16 + lr;
        const int h = n >> 6, d = n & 63;
        u16x4 pk = { f2bf(acc[i][j][0]), f2bf(acc[i][j][1]),
                     f2bf(acc[i][j][2]), f2bf(acc[i][j][3]) };
        *(u16x4*)(Vt + (((size_t)(bb * 12 + h) * 64 + d) << 11) + ss) = pk;
      }
    }
  } else {
    u16* O = (z == 0) ? Qo : Ko;
    const float sc = (z == 0) ? SCALE_Q : 1.0f;
#pragma unroll
    for (int i = 0; i < 4; ++i) {
      const int m0 = mbase + i * 16 + orow;
#pragma unroll
      for (int j = 0; j < 3; ++j) {
        const int n = nbase + j * 16 + lr;
#pragma unroll
        for (int r = 0; r < 4; ++r)
          O[(size_t)(m0 + r) * 768 + n] = f2bf(acc[i][j][r] * sc);
      }
    }
  }
}

// ---------------------------------------------------------------- attention
// 1 wave per block, 32 q-rows, NO LDS, NO barriers. K/V frags loaded direct
// from global (L2-resident), software-pipelined one KV-tile ahead.
// Grid 1536 = exactly 6 blocks/CU; pair (idx, idx+768) -> complementary qt32
// so every CU gets exactly 99 wave-tiles of work.
__global__ __launch_bounds__(64, 2) void attn_kernel(
    const u16* __restrict__ Q, const u16* __restrict__ K,
    const u16* __restrict__ Vt, u16* __restrict__ Ctx)
{
  const int lane = threadIdx.x;
  const int idx = blockIdx.x;
  const int half = (idx >= 768) ? 1 : 0;
  const int base = idx - half * 768;
  const int bh = base % 24;
  const int m  = base / 24;                 // 0..31
  const int qt32 = half ? (2 * m) : (63 - 2 * m);   // heavy blocks dispatch first
  const int bb = bh / 12, hh = bh % 12;
  const int qw0 = qt32 * 32;
  const int l31 = lane & 31;
  const int hi  = lane >> 5;

  const u16* qp = Q  + (size_t)(bb * 2048) * 768 + hh * 64;
  const u16* kp = K  + (size_t)(bb * 2048) * 768 + hh * 64;
  const u16* vp = Vt + (size_t)((bb * 12 + hh) * 64) * 2048;

  // Q fragments (B-operand): n = qw0+l31, k = ks*16 + hi*8 + e
  const u16* qrow = qp + (size_t)(qw0 + l31) * 768 + hi * 8;
  s8b qf[4];
#pragma unroll
  for (int ks = 0; ks < 4; ++ks) qf[ks] = *(const s8b*)(qrow + ks * 16);

  // per-lane row bases for K (A-operand rows = kv) and V^T (B rows = d)
  const u16* krow  = kp + (size_t)l31 * 768 + hi * 8;
  const u16* vrowl = vp + (size_t)l31 * 2048 + hi * 8;
  const u16* vrowh = vp + (size_t)(32 + l31) * 2048 + hi * 8;

  s8b onesf;
#pragma unroll
  for (int i = 0; i < 8; ++i) onesf[i] = (short)0x3F80;   // bf16 1.0

  const f16v z16 = {0.f,0.f,0.f,0.f,0.f,0.f,0.f,0.f,
                    0.f,0.f,0.f,0.f,0.f,0.f,0.f,0.f};
  f16v oac0 = z16, oac1 = z16, lacc = z16;

  const int NT = qt32 >> 1;          // last kv-tile index
  const bool evenq = !(qt32 & 1);

  // ---- prologue: load K/V frags for tile 0
  s8b kf[8], vl[4], vh[4];
#pragma unroll
  for (int mt = 0; mt < 2; ++mt)
#pragma unroll
    for (int ks = 0; ks < 4; ++ks)
      kf[mt * 4 + ks] = *(const s8b*)(krow + (size_t)(mt * 32) * 768 + ks * 16);
#pragma unroll
  for (int mt = 0; mt < 2; ++mt)
#pragma unroll
    for (int k2 = 0; k2 < 2; ++k2) {
      vl[mt * 2 + k2] = *(const s8b*)(vrowl + mt * 32 + k2 * 16);
      vh[mt * 2 + k2] = *(const s8b*)(vrowh + mt * 32 + k2 * 16);
    }

  for (int t = 0; t <= NT; ++t) {
    const int kv0 = t << 6;
    const bool last = (t == NT);
    const bool do1 = !(last && evenq);   // mt1 fully masked on even-q diag

    // ---- S^T = K * Q^T
    f16v st0 = z16, st1 = z16;
    __builtin_amdgcn_s_setprio(1);
#pragma unroll
    for (int ks = 0; ks < 4; ++ks)
      st0 = __builtin_amdgcn_mfma_f32_32x32x16_bf16(kf[ks], qf[ks], st0, 0, 0, 0);
    if (do1) {
#pragma unroll
      for (int ks = 0; ks < 4; ++ks)
        st1 = __builtin_amdgcn_mfma_f32_32x32x16_bf16(kf[4 + ks], qf[ks], st1, 0, 0, 0);
    }
    __builtin_amdgcn_s_setprio(0);

    // ---- prefetch K(t+1) (kf consumed by the MFMAs above)
    if (!last) {
      const size_t ko = (size_t)(kv0 + 64) * 768;
#pragma unroll
      for (int mt = 0; mt < 2; ++mt)
#pragma unroll
        for (int ks = 0; ks < 4; ++ks)
          kf[mt * 4 + ks] = *(const s8b*)(krow + ko + (size_t)(mt * 32) * 768 + ks * 16);
    }

    // ---- P = exp2(S'), causal mask on diagonal tile
    // diag predicate is t-independent: kv_local crow(r,hi) <= q_local l31
    float p0[16], p1[16];
    if (last) {
      if (evenq) {
#pragma unroll
        for (int r = 0; r < 16; ++r) {
          const int crow = (r & 3) + 8 * (r >> 2) + 4 * hi;
          p0[r] = (crow <= l31) ? exp2f(st0[r]) : 0.f;
        }
      } else {
#pragma unroll
        for (int r = 0; r < 16; ++r) p0[r] = exp2f(st0[r]);
#pragma unroll
        for (int r = 0; r < 16; ++r) {
          const int crow = (r & 3) + 8 * (r >> 2) + 4 * hi;
          p1[r] = (crow <= l31) ? exp2f(st1[r]) : 0.f;
        }
      }
    } else {
#pragma unroll
      for (int r = 0; r < 16; ++r) p0[r] = exp2f(st0[r]);
#pragma unroll
      for (int r = 0; r < 16; ++r) p1[r] = exp2f(st1[r]);
    }

    // ---- pack P -> A-frags, PV + l MFMAs
#pragma unroll
    for (int mt = 0; mt < 2; ++mt) {
      if (mt == 1 && !do1) break;
      const float* pp = (mt == 0) ? p0 : p1;
      u32 pk0 = cvtpk_bf16(pp[0],  pp[1]);
      u32 pk1 = cvtpk_bf16(pp[2],  pp[3]);
      u32 pk2 = cvtpk_bf16(pp[4],  pp[5]);
      u32 pk3 = cvtpk_bf16(pp[6],  pp[7]);
      u32 pk4 = cvtpk_bf16(pp[8],  pp[9]);
      u32 pk5 = cvtpk_bf16(pp[10], pp[11]);
      u32 pk6 = cvtpk_bf16(pp[12], pp[13]);
      u32 pk7 = cvtpk_bf16(pp[14], pp[15]);
      plswap(pk0, pk2);
      plswap(pk1, pk3);
      plswap(pk4, pk6);
      plswap(pk5, pk7);
      u32x4 w0 = { pk0, pk1, pk2, pk3 };
      u32x4 w1 = { pk4, pk5, pk6, pk7 };
      s8b pa0 = __builtin_bit_cast(s8b, w0);
      s8b pa1 = __builtin_bit_cast(s8b, w1);
      __builtin_amdgcn_s_setprio(1);
      oac0 = __builtin_amdgcn_mfma_f32_32x32x16_bf16(pa0, vl[mt * 2 + 0], oac0, 0, 0, 0);
      oac0 = __builtin_amdgcn_mfma_f32_32x32x16_bf16(pa1, vl[mt * 2 + 1], oac0, 0, 0, 0);
      oac1 = __builtin_amdgcn_mfma_f32_32x32x16_bf16(pa0, vh[mt * 2 + 0], oac1, 0, 0, 0);
      oac1 = __builtin_amdgcn_mfma_f32_32x32x16_bf16(pa1, vh[mt * 2 + 1], oac1, 0, 0, 0);
      lacc = __builtin_amdgcn_mfma_f32_32x32x16_bf16(pa0, onesf, lacc, 0, 0, 0);
      lacc = __builtin_amdgcn_mfma_f32_32x32x16_bf16(pa1, onesf, lacc, 0, 0, 0);
      __builtin_amdgcn_s_setprio(0);
    }

    // ---- prefetch V(t+1) (vl/vh consumed by PV above)
    if (!last) {
      const int vo = kv0 + 64;
#pragma unroll
      for (int mt = 0; mt < 2; ++mt)
#pragma unroll
        for (int k2 = 0; k2 < 2; ++k2) {
          vl[mt * 2 + k2] = *(const s8b*)(vrowl + vo + mt * 32 + k2 * 16);
          vh[mt * 2 + k2] = *(const s8b*)(vrowh + vo + mt * 32 + k2 * 16);
        }
    }
  }

  // ---- normalize + store ctx (lacc rows match oac rows exactly)
  u16* cp = Ctx + ((size_t)(bb * 2048) * 768) + hh * 64;
  float inv[16];
#pragma unroll
  for (int r = 0; r < 16; ++r) inv[r] = 1.0f / lacc[r];
#pragma unroll
  for (int r = 0; r < 16; ++r) {
    const int row = qw0 + (r & 3) + 8 * (r >> 2) + 4 * hi;
    cp[(size_t)row * 768 + l31]      = f2bf(oac0[r] * inv[r]);
    cp[(size_t)row * 768 + 32 + l31] = f2bf(oac1[r] * inv[r]);
  }
}

// ---------------------------------------------------------------- output GEMM
__global__ __launch_bounds__(256) void out_gemm(
    const u16* __restrict__ A, const u16* __restrict__ W,
    const float* __restrict__ bias, float* __restrict__ Out)
{
  __shared__ u16 At[2][64][64];
  __shared__ u16 Bt[2][64][64];
  const int lane = threadIdx.x & 63;
  const int w    = threadIdx.x >> 6;
  const int wr = w >> 1, wc = w & 1;
  const int mb = blockIdx.x * 64;
  const int nb = blockIdx.y * 64;

  const int lr = lane & 15;
  const int cl = lane >> 4;
  const int srow = lane >> 3;
  const int sx = (lane & 7) ^ srow;

  const f4 fz = {0.f, 0.f, 0.f, 0.f};
  f4 acc[2][2];
#pragma unroll
  for (int i = 0; i < 2; ++i)
#pragma unroll
    for (int j = 0; j < 2; ++j) acc[i][j] = fz;

  const u16* a0 = A + (size_t)mb * 768;
  const u16* b0 = W + (size_t)nb * 768;

#define OUT_STAGE(d, k0)                                                     \
  {                                                                          \
    const int r0 = w * 16;                                                   \
    gl_lds16(a0 + (size_t)(r0 + srow) * 768 + (k0) + sx * 8, &At[d][r0][0]); \
    gl_lds16(a0 + (size_t)(r0 + 8 + srow) * 768 + (k0) + sx * 8, &At[d][r0 + 8][0]); \
    gl_lds16(b0 + (size_t)(r0 + srow) * 768 + (k0) + sx * 8, &Bt[d][r0][0]); \
    gl_lds16(b0 + (size_t)(r0 + 8 + srow) * 768 + (k0) + sx * 8, &Bt[d][r0 + 8][0]); \
  }

  OUT_STAGE(0, 0);
  __syncthreads();
  int db = 0;
  for (int t = 0; t < 12; ++t) {
    if (t < 11) OUT_STAGE(db ^ 1, (t + 1) * 64);
#pragma unroll
    for (int h = 0; h < 2; ++h) {
      s8b af[2], bf[2];
#pragma unroll
      for (int i = 0; i < 2; ++i) {
        const int rr = wr * 32 + i * 16 + lr;
        af[i] = *(const s8b*)&At[db][rr][((h * 4 + cl) ^ (rr & 7)) * 8];
      }
#pragma unroll
      for (int j = 0; j < 2; ++j) {
        const int rr = wc * 32 + j * 16 + lr;
        bf[j] = *(const s8b*)&Bt[db][rr][((h * 4 + cl) ^ (rr & 7)) * 8];
      }
#pragma unroll
      for (int i = 0; i < 2; ++i)
#pragma unroll
        for (int j = 0; j < 2; ++j)
          acc[i][j] = __builtin_amdgcn_mfma_f32_16x16x32_bf16(af[i], bf[j], acc[i][j], 0, 0, 0);
    }
    __syncthreads();
    db ^= 1;
  }

  const int orow = cl * 4;
#pragma unroll
  for (int j = 0; j < 2; ++j) {
    const int n = nb + wc * 32 + j * 16 + lr;
    const float bn = bias[n];
#pragma unroll
    for (int i = 0; i < 2; ++i) {
      const int m0 = mb + wr * 32 + i * 16 + orow;
#pragma unroll
      for (int r = 0; r < 4; ++r)
        Out[(size_t)(m0 + r) * 768 + n] = acc[i][j][r] + bn;
    }
  }
}

// ---------------------------------------------------------------- launch
extern "C" void kernel_launch(void* const* d_in, const int* in_sizes, int n_in,
                              void* d_out, int out_size, void* d_ws, size_t ws_size,
                              hipStream_t stream) {
  const float* emb = (const float*)d_in[0];
  const float* Wq  = (const float*)d_in[1];
  const float* Wk  = (const float*)d_in[2];
  const float* Wv  = (const float*)d_in[3];
  const float* Wo  = (const float*)d_in[4];
  const float* bo  = (const float*)d_in[5];

  char* ws = (char*)d_ws;
  const size_t SZ_X = (size_t)4096 * 768 * 2;
  const size_t SZ_W = (size_t)768 * 768 * 2;
  u16* Xb   = (u16*)(ws);
  u16* Wqb  = (u16*)(ws + SZ_X);
  u16* Wkb  = (u16*)(ws + SZ_X + SZ_W);
  u16* Wvb  = (u16*)(ws + SZ_X + 2 * SZ_W);
  u16* Wob  = (u16*)(ws + SZ_X + 3 * SZ_W);
  u16* Qb   = (u16*)(ws + SZ_X + 4 * SZ_W);
  u16* Kb   = (u16*)(ws + 2 * SZ_X + 4 * SZ_W);
  u16* Vtb  = (u16*)(ws + 3 * SZ_X + 4 * SZ_W);
  u16* Ctxb = (u16*)(ws + 4 * SZ_X + 4 * SZ_W);

  cvt_all<<<2048, 256, 0, stream>>>(emb, Wq, Wk, Wv, Wo, Xb, Wqb, Wkb, Wvb, Wob);
  qkv_gemm<<<dim3(32, 8, 3), 256, 0, stream>>>(Xb, Wqb, Wkb, Wvb, Qb, Kb, Vtb);
  attn_kernel<<<1536, 64, 0, stream>>>(Qb, Kb, Vtb, Ctxb);
  out_gemm<<<dim3(64, 12), 256, 0, stream>>>(Ctxb, Wob, bo, (float*)d_out);
}

// Round 5
// 89.959 us; speedup vs baseline: 3.2153x; 1.1216x over previous
//
#include <hip/hip_runtime.h>
#include <math.h>

typedef unsigned short u16;
typedef unsigned int u32;
typedef short s8b __attribute__((ext_vector_type(8)));     // 8 x bf16 (raw shorts)
typedef float f4 __attribute__((ext_vector_type(4)));
typedef float f16v __attribute__((ext_vector_type(16)));
typedef unsigned short u16x4 __attribute__((ext_vector_type(4)));
typedef unsigned int u32x4 __attribute__((ext_vector_type(4)));
typedef float f32x4 __attribute__((ext_vector_type(4)));

// fold 1/sqrt(64) * log2(e) into Q so softmax uses exp2 directly
#define SCALE_Q 0.18033688011112042f

__device__ __forceinline__ u16 f2bf(float f) {
  u32 u = __builtin_bit_cast(u32, f);
  u += 0x7fffu + ((u >> 16) & 1u);   // RNE
  return (u16)(u >> 16);
}

// async global->LDS, 16B per lane
__device__ __forceinline__ void gl_lds16(const u16* g, u16* l) {
  __builtin_amdgcn_global_load_lds(
      (const __attribute__((address_space(1))) u32*)g,
      (__attribute__((address_space(3))) u32*)l, 16, 0, 0);
}

__device__ __forceinline__ u32 cvtpk_bf16(float lo, float hi) {
  u32 r;
  asm volatile("v_cvt_pk_bf16_f32 %0, %1, %2" : "=v"(r) : "v"(lo), "v"(hi));
  return r;
}

__device__ __forceinline__ void plswap(u32& a, u32& b) {
  asm volatile("v_permlane32_swap_b32 %0, %1" : "+v"(a), "+v"(b));
}

// ---------------------------------------------------------------- convert
__global__ __launch_bounds__(256) void cvt_all(
    const float* __restrict__ e, const float* __restrict__ wq,
    const float* __restrict__ wk, const float* __restrict__ wv,
    const float* __restrict__ wo,
    u16* __restrict__ eo, u16* __restrict__ wqo, u16* __restrict__ wko,
    u16* __restrict__ wvo, u16* __restrict__ woo)
{
  const int EQ4 = 786432;
  const int WQ4 = 147456;
  const int TOT = EQ4 + 4 * WQ4;
  int i = blockIdx.x * 256 + threadIdx.x;
  const int stride = gridDim.x * 256;
  for (; i < TOT; i += stride) {
    const float* s; u16* d; int off;
    if (i < EQ4) { s = e; d = eo; off = i; }
    else {
      int j = i - EQ4; int w = j / WQ4; off = j - w * WQ4;
      s = (w == 0) ? wq : (w == 1) ? wk : (w == 2) ? wv : wo;
      d = (w == 0) ? wqo : (w == 1) ? wko : (w == 2) ? wvo : woo;
    }
    f32x4 v = ((const f32x4*)s)[off];
    u16x4 o = { f2bf(v[0]), f2bf(v[1]), f2bf(v[2]), f2bf(v[3]) };
    ((u16x4*)d)[off] = o;
  }
}

// ---------------------------------------------------------------- QKV GEMM
// 128x96 tile, BK=32, grid (32,8,3)=768 = 3 blocks/CU.
// Epilogues write FRAGMENT-MAJOR layouts consumed by attn:
//   Qf/Kf: [(b*12+h)*64 + g32][ks 0..3][lane 0..63][e 0..7]   (g32 = s>>5)
//   Vf   : [(b*12+h)*128 + g16][dhalf][lane][e]               (g16 = s>>4)
__global__ __launch_bounds__(256) void qkv_gemm(
    const u16* __restrict__ X, const u16* __restrict__ Wq,
    const u16* __restrict__ Wk, const u16* __restrict__ Wv,
    u16* __restrict__ Qf, u16* __restrict__ Kf, u16* __restrict__ Vf)
{
  __shared__ u16 At[2][128][32];
  __shared__ u16 Bt[2][96][32];
  const int lane = threadIdx.x & 63;
  const int w    = threadIdx.x >> 6;
  const int wr = w >> 1, wc = w & 1;
  const int mb = blockIdx.x * 128;
  const int nb = blockIdx.y * 96;
  const int z  = blockIdx.z;
  const u16* W = (z == 0) ? Wq : (z == 1) ? Wk : Wv;

  const int lr = lane & 15;
  const int cl = lane >> 4;             // k-chunk 0..3
  const int srow = lane >> 2;           // staging row 0..15
  const int sx = (lane & 3) ^ (srow & 3);

  const f4 fz = {0.f, 0.f, 0.f, 0.f};
  f4 acc[4][3];
#pragma unroll
  for (int i = 0; i < 4; ++i)
#pragma unroll
    for (int j = 0; j < 3; ++j) acc[i][j] = fz;

  const u16* a0 = X + (size_t)mb * 768;
  const u16* b0 = W + (size_t)nb * 768;

#define QKV_STAGE(d, k0)                                                       \
  {                                                                            \
    gl_lds16(a0 + (size_t)(w * 32 + srow) * 768 + (k0) + sx * 8,               \
             &At[d][w * 32][0]);                                               \
    gl_lds16(a0 + (size_t)(w * 32 + 16 + srow) * 768 + (k0) + sx * 8,          \
             &At[d][w * 32 + 16][0]);                                          \
    if (w < 3) {                                                               \
      gl_lds16(b0 + (size_t)(w * 32 + srow) * 768 + (k0) + sx * 8,             \
               &Bt[d][w * 32][0]);                                             \
      gl_lds16(b0 + (size_t)(w * 32 + 16 + srow) * 768 + (k0) + sx * 8,        \
               &Bt[d][w * 32 + 16][0]);                                        \
    }                                                                          \
  }

  QKV_STAGE(0, 0);
  __syncthreads();
  int db = 0;
  for (int t = 0; t < 24; ++t) {
    if (t < 23) QKV_STAGE(db ^ 1, (t + 1) * 32);
    s8b af[4], bf[3];
#pragma unroll
    for (int i = 0; i < 4; ++i) {
      const int rr = wr * 64 + i * 16 + lr;
      af[i] = *(const s8b*)&At[db][rr][(cl ^ (rr & 3)) * 8];
    }
#pragma unroll
    for (int j = 0; j < 3; ++j) {
      const int rr = wc * 48 + j * 16 + lr;
      bf[j] = *(const s8b*)&Bt[db][rr][(cl ^ (rr & 3)) * 8];
    }
#pragma unroll
    for (int i = 0; i < 4; ++i)
#pragma unroll
      for (int j = 0; j < 3; ++j)
        acc[i][j] = __builtin_amdgcn_mfma_f32_16x16x32_bf16(af[i], bf[j], acc[i][j], 0, 0, 0);
    __syncthreads();
    db ^= 1;
  }

  const int mbase = mb + wr * 64;
  const int nbase = nb + wc * 48;
  const int orow = cl * 4;
  if (z == 2) {
    // V fragment-major
#pragma unroll
    for (int i = 0; i < 4; ++i) {
      const int m0 = mbase + i * 16 + orow;   // kv token row; m0&7 in {0,4}
      const int b  = m0 >> 11, s0 = m0 & 2047;
      const int g16 = s0 >> 4, hi8 = (s0 >> 3) & 1, e0 = s0 & 7;
#pragma unroll
      for (int j = 0; j < 3; ++j) {
        const int n = nbase + j * 16 + lr;
        const int h = n >> 6, d6 = n & 63;
        const int dh = d6 >> 5, l31v = d6 & 31;
        u16x4 pk = { f2bf(acc[i][j][0]), f2bf(acc[i][j][1]),
                     f2bf(acc[i][j][2]), f2bf(acc[i][j][3]) };
        u16* dst = Vf + ((((size_t)(b * 12 + h) * 128 + g16) * 2 + dh) * 64
                         + hi8 * 32 + l31v) * 8 + e0;
        *(u16x4*)dst = pk;
      }
    }
  } else {
    // Q/K fragment-major
    u16* O = (z == 0) ? Qf : Kf;
    const float sc = (z == 0) ? SCALE_Q : 1.0f;
#pragma unroll
    for (int i = 0; i < 4; ++i) {
      const int m0 = mbase + i * 16 + orow;   // token row
      const int b  = m0 >> 11, s0 = m0 & 2047;
      const int g32 = s0 >> 5;
#pragma unroll
      for (int j = 0; j < 3; ++j) {
        const int n = nbase + j * 16 + lr;
        const int h = n >> 6, k6 = n & 63;
        const int ks = k6 >> 4, hi8 = (k6 >> 3) & 1, e = k6 & 7;
        u16* dst = O + ((((size_t)(b * 12 + h) * 64 + g32) * 4 + ks) * 64
                        + hi8 * 32) * 8 + e;
#pragma unroll
        for (int r = 0; r < 4; ++r)
          dst[(size_t)((s0 & 31) + r) * 8] = f2bf(acc[i][j][r] * sc);
      }
    }
  }
}

// ---------------------------------------------------------------- attention
// 1 wave per block, 32 q-rows, NO LDS, NO barriers. All loads are
// fragment-major: base + lane*16 -> fully coalesced 1KB/instr.
__global__ __launch_bounds__(64, 2) void attn_kernel(
    const u16* __restrict__ Qf, const u16* __restrict__ Kf,
    const u16* __restrict__ Vf, u16* __restrict__ Ctx)
{
  const int lane = threadIdx.x;
  const int idx = blockIdx.x;
  const int half = (idx >= 768) ? 1 : 0;
  const int base = idx - half * 768;
  const int bh = base % 24;
  const int m  = base / 24;                 // 0..31
  const int qt32 = half ? (2 * m) : (63 - 2 * m);
  const int bb = bh / 12, hh = bh % 12;
  const int qw0 = qt32 * 32;
  const int l31 = lane & 31;
  const int hi  = lane >> 5;

  // fragment-major bases for this (b,h)
  const u16* qfp = Qf + ((size_t)bh * 64 + qt32) * 4 * 512;   // 512 u16 per frag-block
  const u16* kfp = Kf + (size_t)bh * 64 * 4 * 512;
  const u16* vfp = Vf + (size_t)bh * 128 * 2 * 512;
  const int loff = lane * 8;

  s8b qf[4];
#pragma unroll
  for (int ks = 0; ks < 4; ++ks)
    qf[ks] = *(const s8b*)(qfp + ks * 512 + loff);

  s8b onesf;
#pragma unroll
  for (int i = 0; i < 8; ++i) onesf[i] = (short)0x3F80;   // bf16 1.0

  const f16v z16 = {0.f,0.f,0.f,0.f,0.f,0.f,0.f,0.f,
                    0.f,0.f,0.f,0.f,0.f,0.f,0.f,0.f};
  f16v oac0 = z16, oac1 = z16, lacc = z16;

  const int NT = qt32 >> 1;          // last kv-tile index
  const bool evenq = !(qt32 & 1);

  // ---- prologue: load K/V frags for tile 0
  // kf[mt*4+ks] at frag-block g32=2t+mt, slot ks; v at g16=4t+2mt+k2, dhalf
  s8b kf[8], vl[4], vh[4];
#pragma unroll
  for (int mt = 0; mt < 2; ++mt)
#pragma unroll
    for (int ks = 0; ks < 4; ++ks)
      kf[mt * 4 + ks] = *(const s8b*)(kfp + (mt * 4 + ks) * 512 + loff);
#pragma unroll
  for (int mt = 0; mt < 2; ++mt)
#pragma unroll
    for (int k2 = 0; k2 < 2; ++k2) {
      const int g16 = mt * 2 + k2;
      vl[mt * 2 + k2] = *(const s8b*)(vfp + (g16 * 2 + 0) * 512 + loff);
      vh[mt * 2 + k2] = *(const s8b*)(vfp + (g16 * 2 + 1) * 512 + loff);
    }

  for (int t = 0; t <= NT; ++t) {
    const bool last = (t == NT);
    const bool do1 = !(last && evenq);   // mt1 fully masked on even-q diag

    // ---- S^T = K * Q^T
    f16v st0 = z16, st1 = z16;
    __builtin_amdgcn_s_setprio(1);
#pragma unroll
    for (int ks = 0; ks < 4; ++ks)
      st0 = __builtin_amdgcn_mfma_f32_32x32x16_bf16(kf[ks], qf[ks], st0, 0, 0, 0);
    if (do1) {
#pragma unroll
      for (int ks = 0; ks < 4; ++ks)
        st1 = __builtin_amdgcn_mfma_f32_32x32x16_bf16(kf[4 + ks], qf[ks], st1, 0, 0, 0);
    }
    __builtin_amdgcn_s_setprio(0);

    // ---- prefetch K(t+1) (kf consumed above)
    if (!last) {
      const u16* kn = kfp + (size_t)(2 * t + 2) * 4 * 512;
#pragma unroll
      for (int mt = 0; mt < 2; ++mt)
#pragma unroll
        for (int ks = 0; ks < 4; ++ks)
          kf[mt * 4 + ks] = *(const s8b*)(kn + (mt * 4 + ks) * 512 + loff);
    }

    // ---- P = exp2(S'), causal mask on diagonal tile
    float p0[16], p1[16];
    if (last) {
      if (evenq) {
#pragma unroll
        for (int r = 0; r < 16; ++r) {
          const int crow = (r & 3) + 8 * (r >> 2) + 4 * hi;
          p0[r] = (crow <= l31) ? exp2f(st0[r]) : 0.f;
        }
      } else {
#pragma unroll
        for (int r = 0; r < 16; ++r) p0[r] = exp2f(st0[r]);
#pragma unroll
        for (int r = 0; r < 16; ++r) {
          const int crow = (r & 3) + 8 * (r >> 2) + 4 * hi;
          p1[r] = (crow <= l31) ? exp2f(st1[r]) : 0.f;
        }
      }
    } else {
#pragma unroll
      for (int r = 0; r < 16; ++r) p0[r] = exp2f(st0[r]);
#pragma unroll
      for (int r = 0; r < 16; ++r) p1[r] = exp2f(st1[r]);
    }

    // ---- pack P -> A-frags, PV + l MFMAs
#pragma unroll
    for (int mt = 0; mt < 2; ++mt) {
      if (mt == 1 && !do1) break;
      const float* pp = (mt == 0) ? p0 : p1;
      u32 pk0 = cvtpk_bf16(pp[0],  pp[1]);
      u32 pk1 = cvtpk_bf16(pp[2],  pp[3]);
      u32 pk2 = cvtpk_bf16(pp[4],  pp[5]);
      u32 pk3 = cvtpk_bf16(pp[6],  pp[7]);
      u32 pk4 = cvtpk_bf16(pp[8],  pp[9]);
      u32 pk5 = cvtpk_bf16(pp[10], pp[11]);
      u32 pk6 = cvtpk_bf16(pp[12], pp[13]);
      u32 pk7 = cvtpk_bf16(pp[14], pp[15]);
      plswap(pk0, pk2);
      plswap(pk1, pk3);
      plswap(pk4, pk6);
      plswap(pk5, pk7);
      u32x4 w0 = { pk0, pk1, pk2, pk3 };
      u32x4 w1 = { pk4, pk5, pk6, pk7 };
      s8b pa0 = __builtin_bit_cast(s8b, w0);
      s8b pa1 = __builtin_bit_cast(s8b, w1);
      __builtin_amdgcn_s_setprio(1);
      oac0 = __builtin_amdgcn_mfma_f32_32x32x16_bf16(pa0, vl[mt * 2 + 0], oac0, 0, 0, 0);
      oac0 = __builtin_amdgcn_mfma_f32_32x32x16_bf16(pa1, vl[mt * 2 + 1], oac0, 0, 0, 0);
      oac1 = __builtin_amdgcn_mfma_f32_32x32x16_bf16(pa0, vh[mt * 2 + 0], oac1, 0, 0, 0);
      oac1 = __builtin_amdgcn_mfma_f32_32x32x16_bf16(pa1, vh[mt * 2 + 1], oac1, 0, 0, 0);
      lacc = __builtin_amdgcn_mfma_f32_32x32x16_bf16(pa0, onesf, lacc, 0, 0, 0);
      lacc = __builtin_amdgcn_mfma_f32_32x32x16_bf16(pa1, onesf, lacc, 0, 0, 0);
      __builtin_amdgcn_s_setprio(0);
    }

    // ---- prefetch V(t+1) (vl/vh consumed above)
    if (!last) {
      const u16* vn = vfp + (size_t)(4 * t + 4) * 2 * 512;
#pragma unroll
      for (int mt = 0; mt < 2; ++mt)
#pragma unroll
        for (int k2 = 0; k2 < 2; ++k2) {
          const int g16 = mt * 2 + k2;
          vl[mt * 2 + k2] = *(const s8b*)(vn + (g16 * 2 + 0) * 512 + loff);
          vh[mt * 2 + k2] = *(const s8b*)(vn + (g16 * 2 + 1) * 512 + loff);
        }
    }
  }

  // ---- normalize + store ctx
  u16* cp = Ctx + ((size_t)(bb * 2048) * 768) + hh * 64;
  float inv[16];
#pragma unroll
  for (int r = 0; r < 16; ++r) inv[r] = 1.0f / lacc[r];
#pragma unroll
  for (int r = 0; r < 16; ++r) {
    const int row = qw0 + (r & 3) + 8 * (r >> 2) + 4 * hi;
    cp[(size_t)row * 768 + l31]      = f2bf(oac0[r] * inv[r]);
    cp[(size_t)row * 768 + 32 + l31] = f2bf(oac1[r] * inv[r]);
  }
}

// ---------------------------------------------------------------- output GEMM
__global__ __launch_bounds__(256) void out_gemm(
    const u16* __restrict__ A, const u16* __restrict__ W,
    const float* __restrict__ bias, float* __restrict__ Out)
{
  __shared__ u16 At[2][64][64];
  __shared__ u16 Bt[2][64][64];
  const int lane = threadIdx.x & 63;
  const int w    = threadIdx.x >> 6;
  const int wr = w >> 1, wc = w & 1;
  const int mb = blockIdx.x * 64;
  const int nb = blockIdx.y * 64;

  const int lr = lane & 15;
  const int cl = lane >> 4;
  const int srow = lane >> 3;
  const int sx = (lane & 7) ^ srow;

  const f4 fz = {0.f, 0.f, 0.f, 0.f};
  f4 acc[2][2];
#pragma unroll
  for (int i = 0; i < 2; ++i)
#pragma unroll
    for (int j = 0; j < 2; ++j) acc[i][j] = fz;

  const u16* a0 = A + (size_t)mb * 768;
  const u16* b0 = W + (size_t)nb * 768;

#define OUT_STAGE(d, k0)                                                     \
  {                                                                          \
    const int r0 = w * 16;                                                   \
    gl_lds16(a0 + (size_t)(r0 + srow) * 768 + (k0) + sx * 8, &At[d][r0][0]); \
    gl_lds16(a0 + (size_t)(r0 + 8 + srow) * 768 + (k0) + sx * 8, &At[d][r0 + 8][0]); \
    gl_lds16(b0 + (size_t)(r0 + srow) * 768 + (k0) + sx * 8, &Bt[d][r0][0]); \
    gl_lds16(b0 + (size_t)(r0 + 8 + srow) * 768 + (k0) + sx * 8, &Bt[d][r0 + 8][0]); \
  }

  OUT_STAGE(0, 0);
  __syncthreads();
  int db = 0;
  for (int t = 0; t < 12; ++t) {
    if (t < 11) OUT_STAGE(db ^ 1, (t + 1) * 64);
#pragma unroll
    for (int h = 0; h < 2; ++h) {
      s8b af[2], bf[2];
#pragma unroll
      for (int i = 0; i < 2; ++i) {
        const int rr = wr * 32 + i * 16 + lr;
        af[i] = *(const s8b*)&At[db][rr][((h * 4 + cl) ^ (rr & 7)) * 8];
      }
#pragma unroll
      for (int j = 0; j < 2; ++j) {
        const int rr = wc * 32 + j * 16 + lr;
        bf[j] = *(const s8b*)&Bt[db][rr][((h * 4 + cl) ^ (rr & 7)) * 8];
      }
#pragma unroll
      for (int i = 0; i < 2; ++i)
#pragma unroll
        for (int j = 0; j < 2; ++j)
          acc[i][j] = __builtin_amdgcn_mfma_f32_16x16x32_bf16(af[i], bf[j], acc[i][j], 0, 0, 0);
    }
    __syncthreads();
    db ^= 1;
  }

  const int orow = cl * 4;
#pragma unroll
  for (int j = 0; j < 2; ++j) {
    const int n = nb + wc * 32 + j * 16 + lr;
    const float bn = bias[n];
#pragma unroll
    for (int i = 0; i < 2; ++i) {
      const int m0 = mb + wr * 32 + i * 16 + orow;
#pragma unroll
      for (int r = 0; r < 4; ++r)
        Out[(size_t)(m0 + r) * 768 + n] = acc[i][j][r] + bn;
    }
  }
}

// ---------------------------------------------------------------- launch
extern "C" void kernel_launch(void* const* d_in, const int* in_sizes, int n_in,
                              void* d_out, int out_size, void* d_ws, size_t ws_size,
                              hipStream_t stream) {
  const float* emb = (const float*)d_in[0];
  const float* Wq  = (const float*)d_in[1];
  const float* Wk  = (const float*)d_in[2];
  const float* Wv  = (const float*)d_in[3];
  const float* Wo  = (const float*)d_in[4];
  const float* bo  = (const float*)d_in[5];

  char* ws = (char*)d_ws;
  const size_t SZ_X = (size_t)4096 * 768 * 2;
  const size_t SZ_W = (size_t)768 * 768 * 2;
  u16* Xb   = (u16*)(ws);
  u16* Wqb  = (u16*)(ws + SZ_X);
  u16* Wkb  = (u16*)(ws + SZ_X + SZ_W);
  u16* Wvb  = (u16*)(ws + SZ_X + 2 * SZ_W);
  u16* Wob  = (u16*)(ws + SZ_X + 3 * SZ_W);
  u16* Qfb  = (u16*)(ws + SZ_X + 4 * SZ_W);
  u16* Kfb  = (u16*)(ws + 2 * SZ_X + 4 * SZ_W);
  u16* Vfb  = (u16*)(ws + 3 * SZ_X + 4 * SZ_W);
  u16* Ctxb = (u16*)(ws + 4 * SZ_X + 4 * SZ_W);

  cvt_all<<<2048, 256, 0, stream>>>(emb, Wq, Wk, Wv, Wo, Xb, Wqb, Wkb, Wvb, Wob);
  qkv_gemm<<<dim3(32, 8, 3), 256, 0, stream>>>(Xb, Wqb, Wkb, Wvb, Qfb, Kfb, Vfb);
  attn_kernel<<<1536, 64, 0, stream>>>(Qfb, Kfb, Vfb, Ctxb);
  out_gemm<<<dim3(64, 12), 256, 0, stream>>>(Ctxb, Wob, bo, (float*)d_out);
}